// Round 2
// baseline (1097.999 us; speedup 1.0000x reference)
//
#include <hip/hip_runtime.h>

#define D_MODEL 512
#define N_HEADS 8
#define D_K     64
#define BATCH   4
#define Q_LEN   1024
#define M_LEN   1024
#define K_LEN   2048

// ---------------------------------------------------------------------------
// Generic fp32 tiled GEMM: C[M][N] = A[M][K] * B[K][N] + bias[N]
// mode 0: A rows are concat(mem, inputs) per batch (2048 rows/batch, K=512)
// mode 1: A = a0, plain row-major
// ---------------------------------------------------------------------------
template<int BM, int BN, int TM, int TN>
__global__ __launch_bounds__(256)
void gemm_bias(const float* __restrict__ a0, const float* __restrict__ a1,
               const float* __restrict__ B, const float* __restrict__ bias,
               float* __restrict__ C, int N, int K, int mode) {
    __shared__ float a_s[16][BM + 4];
    __shared__ float b_s[16][BN + 4];

    const int tid  = threadIdx.x;
    const int row0 = blockIdx.x * BM;
    const int col0 = blockIdx.y * BN;
    const int tm   = tid / (BN / TN);
    const int tn   = tid % (BN / TN);

    float acc[TM][TN];
#pragma unroll
    for (int i = 0; i < TM; i++)
#pragma unroll
        for (int j = 0; j < TN; j++) acc[i][j] = 0.f;

    for (int k0 = 0; k0 < K; k0 += 16) {
        // stage A tile (BM x 16), transposed into a_s[k][m]
        for (int idx = tid; idx < BM * 4; idx += 256) {
            int m  = idx >> 2;
            int k4 = idx & 3;
            int row = row0 + m;
            const float* src;
            if (mode == 0) {
                int b = row >> 11;          // /2048
                int t = row & 2047;
                src = (t < M_LEN) ? (a0 + ((size_t)b * M_LEN + t) * K)
                                  : (a1 + ((size_t)b * Q_LEN + (t - M_LEN)) * K);
            } else {
                src = a0 + (size_t)row * K;
            }
            float4 val = *(const float4*)(src + k0 + k4 * 4);
            a_s[k4 * 4 + 0][m] = val.x;
            a_s[k4 * 4 + 1][m] = val.y;
            a_s[k4 * 4 + 2][m] = val.z;
            a_s[k4 * 4 + 3][m] = val.w;
        }
        // stage B tile (16 x BN)
        for (int idx = tid; idx < BN * 4; idx += 256) {
            int kk = idx / (BN / 4);
            int n4 = idx % (BN / 4);
            float4 val = *(const float4*)(B + (size_t)(k0 + kk) * N + col0 + n4 * 4);
            *(float4*)&b_s[kk][n4 * 4] = val;
        }
        __syncthreads();

#pragma unroll
        for (int kk = 0; kk < 16; kk++) {
            float av[TM], bv[TN];
#pragma unroll
            for (int i = 0; i < TM; i += 4)
                *(float4*)&av[i] = *(const float4*)&a_s[kk][tm * TM + i];
#pragma unroll
            for (int j = 0; j < TN; j += 4)
                *(float4*)&bv[j] = *(const float4*)&b_s[kk][tn * TN + j];
#pragma unroll
            for (int i = 0; i < TM; i++)
#pragma unroll
                for (int j = 0; j < TN; j++)
                    acc[i][j] = fmaf(av[i], bv[j], acc[i][j]);
        }
        __syncthreads();
    }

    // epilogue: add bias, store
#pragma unroll
    for (int i = 0; i < TM; i++) {
        int row = row0 + tm * TM + i;
        float* dst = C + (size_t)row * N + col0 + tn * TN;
#pragma unroll
        for (int j = 0; j < TN; j += 4) {
            float4 bv = *(const float4*)(bias + col0 + tn * TN + j);
            float4 o;
            o.x = acc[i][j + 0] + bv.x;
            o.y = acc[i][j + 1] + bv.y;
            o.z = acc[i][j + 2] + bv.z;
            o.w = acc[i][j + 3] + bv.w;
            *(float4*)(dst + j) = o;
        }
    }
}

// ---------------------------------------------------------------------------
// Fused relative attention.
// Per block: (b, head hn, 64-row q tile). Iterates 64-wide k tiles.
// score[q,k] = ( q.K[k] + u.K[k] + q.R[j] + v.R[j] ) / 8,  j = k + 1023 - q
// masked to -1e30 where k > q + M_LEN; online softmax; PV accumulate.
// ---------------------------------------------------------------------------
__global__ __launch_bounds__(256)
void attn_fused(const float* __restrict__ w, const float* __restrict__ rproj,
                const float* __restrict__ u, const float* __restrict__ v,
                float* __restrict__ out) {
    __shared__ float qT [64][68];   // [d][q]   q tile transposed
    __shared__ float ktT[64][68];   // [d][k]   K tile transposed
    __shared__ float vt [64][68];   // [k][d]   V tile
    __shared__ float rtT[64][136];  // [d][t]   R window (128 rows) transposed
    __shared__ float s1 [64][68];   // [q][k] scores (ac);  later reused as pT[k][q]
    __shared__ float s2 [64][136];  // [q][t] window scores (bd)
    __shared__ float uk [64];
    __shared__ float vr [128];
    __shared__ float u_s[64], v_s[64];
    __shared__ float alpha_s[64], l_s[64], m_s[64];

    const int qt  = blockIdx.x;
    const int hn  = blockIdx.y;
    const int b   = blockIdx.z;
    const int q0  = qt * 64;
    const int tid = threadIdx.x;
    const int tm  = tid >> 4;   // 0..15  (GEMM layout: 4 q-rows)
    const int tn  = tid & 15;   // 0..15  (GEMM layout: 4 cols)
    const int qr  = tid >> 2;   // 0..63  (row layout)
    const int kc  = tid & 3;    // 0..3

    // ---- prologue: stage q tile (transposed), u, v; init m/l ----
    for (int idx = tid; idx < 1024; idx += 256) {
        int dq = idx >> 4, d4 = idx & 15;
        const float* src = w + ((size_t)b * K_LEN + M_LEN + q0 + dq) * 1536 + hn * 64 + d4 * 4;
        float4 val = *(const float4*)src;
        qT[d4 * 4 + 0][dq] = val.x;
        qT[d4 * 4 + 1][dq] = val.y;
        qT[d4 * 4 + 2][dq] = val.z;
        qT[d4 * 4 + 3][dq] = val.w;
    }
    if (tid < 16) {
        float4 uu = *(const float4*)(u + hn * 64 + tid * 4);
        u_s[tid * 4 + 0] = uu.x; u_s[tid * 4 + 1] = uu.y;
        u_s[tid * 4 + 2] = uu.z; u_s[tid * 4 + 3] = uu.w;
    } else if (tid < 32) {
        int t2 = tid - 16;
        float4 vv = *(const float4*)(v + hn * 64 + t2 * 4);
        v_s[t2 * 4 + 0] = vv.x; v_s[t2 * 4 + 1] = vv.y;
        v_s[t2 * 4 + 2] = vv.z; v_s[t2 * 4 + 3] = vv.w;
    }
    if (tid < 64) { m_s[tid] = -1e30f; l_s[tid] = 0.f; }

    float o[4][4];
#pragma unroll
    for (int i = 0; i < 4; i++)
#pragma unroll
        for (int j = 0; j < 4; j++) o[i][j] = 0.f;

    const int ntiles = qt + 17;   // covers k <= q0+63+M_LEN

    for (int ti = 0; ti < ntiles; ti++) {
        const int k0 = ti * 64;
        const int jb = k0 + 960 - q0;   // window base: j = jb + (dk + 63 - dq)
        __syncthreads();                // protect LDS from previous iteration

        // ---- stage K,V tiles ----
        for (int idx = tid; idx < 1024; idx += 256) {
            int kk = idx >> 4, d4 = idx & 15;
            const float* base = w + ((size_t)b * K_LEN + k0 + kk) * 1536 + hn * 64 + d4 * 4;
            float4 kv = *(const float4*)(base + 512);
            ktT[d4 * 4 + 0][kk] = kv.x;
            ktT[d4 * 4 + 1][kk] = kv.y;
            ktT[d4 * 4 + 2][kk] = kv.z;
            ktT[d4 * 4 + 3][kk] = kv.w;
            float4 vv = *(const float4*)(base + 1024);
            *(float4*)&vt[kk][d4 * 4] = vv;
        }
        // ---- stage R window (128 rows, clamped) ----
        for (int idx = tid; idx < 2048; idx += 256) {
            int t = idx >> 4, d4 = idx & 15;
            int j = jb + t;
            j = j < 2047 ? j : 2047;    // clamped rows only feed masked scores
            float4 rv = *(const float4*)(rproj + (size_t)j * 512 + hn * 64 + d4 * 4);
            rtT[d4 * 4 + 0][t] = rv.x;
            rtT[d4 * 4 + 1][t] = rv.y;
            rtT[d4 * 4 + 2][t] = rv.z;
            rtT[d4 * 4 + 3][t] = rv.w;
        }
        __syncthreads();

        // ---- uk[k] = u.K[k] ; vr[t] = v.R[t] ----
        if (tid < 64) {
            float s = 0.f;
#pragma unroll 8
            for (int d = 0; d < 64; d++) s = fmaf(u_s[d], ktT[d][tid], s);
            uk[tid] = s;
        } else if (tid < 192) {
            int t = tid - 64;
            float s = 0.f;
#pragma unroll 8
            for (int d = 0; d < 64; d++) s = fmaf(v_s[d], rtT[d][t], s);
            vr[t] = s;
        }

        // ---- merged S1 = qT^T.K (64x64) and S2 = qT^T.Rwindow (64x128) ----
        // shares the qT A-operand loads between both GEMMs
        {
            float acc1[4][4];
            float acc2[4][8];
#pragma unroll
            for (int i = 0; i < 4; i++) {
#pragma unroll
                for (int j = 0; j < 4; j++) acc1[i][j] = 0.f;
#pragma unroll
                for (int j = 0; j < 8; j++) acc2[i][j] = 0.f;
            }
#pragma unroll 4
            for (int d = 0; d < 64; d++) {
                float av[4], bk[4], br0[8];
                *(float4*)av      = *(const float4*)&qT[d][tm * 4];
                *(float4*)bk      = *(const float4*)&ktT[d][tn * 4];
                *(float4*)&br0[0] = *(const float4*)&rtT[d][tn * 8];
                *(float4*)&br0[4] = *(const float4*)&rtT[d][tn * 8 + 4];
#pragma unroll
                for (int i = 0; i < 4; i++) {
#pragma unroll
                    for (int j = 0; j < 4; j++)
                        acc1[i][j] = fmaf(av[i], bk[j], acc1[i][j]);
#pragma unroll
                    for (int j = 0; j < 8; j++)
                        acc2[i][j] = fmaf(av[i], br0[j], acc2[i][j]);
                }
            }
#pragma unroll
            for (int i = 0; i < 4; i++) {
                float4 st; st.x = acc1[i][0]; st.y = acc1[i][1]; st.z = acc1[i][2]; st.w = acc1[i][3];
                *(float4*)&s1[tm * 4 + i][tn * 4] = st;
                float4 st0; st0.x = acc2[i][0]; st0.y = acc2[i][1]; st0.z = acc2[i][2]; st0.w = acc2[i][3];
                float4 st1; st1.x = acc2[i][4]; st1.y = acc2[i][5]; st1.z = acc2[i][6]; st1.w = acc2[i][7];
                *(float4*)&s2[tm * 4 + i][tn * 8]     = st0;
                *(float4*)&s2[tm * 4 + i][tn * 8 + 4] = st1;
            }
        }
        __syncthreads();

        // ---- row phase: mask + online softmax (4 lanes per q row) ----
        float p[16];
        float mloc = -1e30f;
        const int q = q0 + qr;
        {
            float s1v[16], ukv[16];
#pragma unroll
            for (int i = 0; i < 16; i += 4) {
                *(float4*)&s1v[i] = *(const float4*)&s1[qr][kc * 16 + i];
                *(float4*)&ukv[i] = *(const float4*)&uk[kc * 16 + i];
            }
#pragma unroll
            for (int i = 0; i < 16; i++) {
                int dk = kc * 16 + i;
                int t  = dk + 63 - qr;          // 0..126
                float x = (s1v[i] + ukv[i] + s2[qr][t] + vr[t]) * 0.125f;
                if (k0 + dk > q + M_LEN) x = -1e30f;
                p[i] = x;
                mloc = fmaxf(mloc, x);
            }
        }
        mloc = fmaxf(mloc, __shfl_xor(mloc, 1));
        mloc = fmaxf(mloc, __shfl_xor(mloc, 2));
        float mold = m_s[qr];
        float mnew = fmaxf(mold, mloc);
        float alpha = __expf(mold - mnew);
        float lsum = 0.f;
#pragma unroll
        for (int i = 0; i < 16; i++) {
            float pe = __expf(p[i] - mnew);
            p[i] = pe;
            lsum += pe;
        }
        lsum += __shfl_xor(lsum, 1);
        lsum += __shfl_xor(lsum, 2);
        if (kc == 0) {
            m_s[qr]     = mnew;
            l_s[qr]     = l_s[qr] * alpha + lsum;
            alpha_s[qr] = alpha;
        }
        __syncthreads();   // everyone done reading s1/s2 before pT overwrite

        // write P transposed into s1 buffer: pT[k][q]
#pragma unroll
        for (int i = 0; i < 16; i++) s1[kc * 16 + i][qr] = p[i];
        __syncthreads();

        // ---- PV: O += P^T-layout GEMM (64q x 64d over 64 k) ----
        {
#pragma unroll
            for (int i = 0; i < 4; i++) {
                float a = alpha_s[tm * 4 + i];
#pragma unroll
                for (int j = 0; j < 4; j++) o[i][j] *= a;
            }
#pragma unroll 8
            for (int k = 0; k < 64; k++) {
                float av[4], bv[4];
                *(float4*)av = *(const float4*)&s1[k][tm * 4];   // pT
                *(float4*)bv = *(const float4*)&vt[k][tn * 4];
#pragma unroll
                for (int i = 0; i < 4; i++)
#pragma unroll
                    for (int j = 0; j < 4; j++)
                        o[i][j] = fmaf(av[i], bv[j], o[i][j]);
            }
        }
    }

    // ---- epilogue: normalize, store (b, q, n, d) ----
    __syncthreads();
#pragma unroll
    for (int i = 0; i < 4; i++) {
        float inv = 1.f / l_s[tm * 4 + i];
        float4 ov;
        ov.x = o[i][0] * inv; ov.y = o[i][1] * inv;
        ov.z = o[i][2] * inv; ov.w = o[i][3] * inv;
        float* dst = out + (((size_t)b * Q_LEN + q0 + tm * 4 + i) * N_HEADS + hn) * D_K + tn * 4;
        *(float4*)dst = ov;
    }
}

// ---------------------------------------------------------------------------
extern "C" void kernel_launch(void* const* d_in, const int* in_sizes, int n_in,
                              void* d_out, int out_size, void* d_ws, size_t ws_size,
                              hipStream_t stream) {
    (void)in_sizes; (void)n_in; (void)out_size; (void)ws_size;

    const float* inputs = (const float*)d_in[0];
    const float* mem    = (const float*)d_in[1];
    const float* r      = (const float*)d_in[2];
    const float* Wqkv   = (const float*)d_in[3];
    const float* bqkv   = (const float*)d_in[4];
    const float* Wr     = (const float*)d_in[5];
    const float* br     = (const float*)d_in[6];
    const float* Wo     = (const float*)d_in[7];
    const float* bo     = (const float*)d_in[8];
    const float* u      = (const float*)d_in[9];
    const float* v      = (const float*)d_in[10];
    float* out = (float*)d_out;

    float* w     = (float*)d_ws;                   // 8192 x 1536
    float* rproj = w + (size_t)8192 * 1536;        // 2048 x 512
    float* attn  = rproj + (size_t)2048 * 512;     // 4096 x 512 (b,q,n,d)

    // 1) QKV projection on concat(mem, inputs): (8192 x 512) @ (512 x 1536)
    hipLaunchKernelGGL((gemm_bias<128, 128, 8, 8>), dim3(64, 12), dim3(256), 0, stream,
                       mem, inputs, Wqkv, bqkv, w, 1536, 512, 0);
    // 2) R projection: (2048 x 512) @ (512 x 512)
    hipLaunchKernelGGL((gemm_bias<64, 64, 4, 4>), dim3(32, 8), dim3(256), 0, stream,
                       r, r, Wr, br, rproj, 512, 512, 1);
    // 3) fused relative attention
    hipLaunchKernelGGL(attn_fused, dim3(16, 8, 4), dim3(256), 0, stream,
                       w, rproj, u, v, attn);
    // 4) output projection: (4096 x 512) @ (512 x 512)
    hipLaunchKernelGGL((gemm_bias<64, 64, 4, 4>), dim3(64, 8), dim3(256), 0, stream,
                       attn, attn, Wo, bo, out, 512, 512, 1);
}

// Round 3
// 1060.499 us; speedup vs baseline: 1.0354x; 1.0354x over previous
//
#include <hip/hip_runtime.h>

#define D_MODEL 512
#define N_HEADS 8
#define D_K     64
#define BATCH   4
#define Q_LEN   1024
#define M_LEN   1024
#define K_LEN   2048

// ---------------------------------------------------------------------------
// Generic fp32 tiled GEMM: C[M][N] = A[M][K] * B[K][N] + bias[N]
// mode 0: A rows are concat(mem, inputs) per batch (2048 rows/batch, K=512)
// mode 1: A = a0, plain row-major
// ---------------------------------------------------------------------------
template<int BM, int BN, int TM, int TN>
__global__ __launch_bounds__(256)
void gemm_bias(const float* __restrict__ a0, const float* __restrict__ a1,
               const float* __restrict__ B, const float* __restrict__ bias,
               float* __restrict__ C, int N, int K, int mode) {
    __shared__ float a_s[16][BM + 4];
    __shared__ float b_s[16][BN + 4];

    const int tid  = threadIdx.x;
    const int row0 = blockIdx.x * BM;
    const int col0 = blockIdx.y * BN;
    const int tm   = tid / (BN / TN);
    const int tn   = tid % (BN / TN);

    float acc[TM][TN];
#pragma unroll
    for (int i = 0; i < TM; i++)
#pragma unroll
        for (int j = 0; j < TN; j++) acc[i][j] = 0.f;

    for (int k0 = 0; k0 < K; k0 += 16) {
        for (int idx = tid; idx < BM * 4; idx += 256) {
            int m  = idx >> 2;
            int k4 = idx & 3;
            int row = row0 + m;
            const float* src;
            if (mode == 0) {
                int b = row >> 11;
                int t = row & 2047;
                src = (t < M_LEN) ? (a0 + ((size_t)b * M_LEN + t) * K)
                                  : (a1 + ((size_t)b * Q_LEN + (t - M_LEN)) * K);
            } else {
                src = a0 + (size_t)row * K;
            }
            float4 val = *(const float4*)(src + k0 + k4 * 4);
            a_s[k4 * 4 + 0][m] = val.x;
            a_s[k4 * 4 + 1][m] = val.y;
            a_s[k4 * 4 + 2][m] = val.z;
            a_s[k4 * 4 + 3][m] = val.w;
        }
        for (int idx = tid; idx < BN * 4; idx += 256) {
            int kk = idx / (BN / 4);
            int n4 = idx % (BN / 4);
            float4 val = *(const float4*)(B + (size_t)(k0 + kk) * N + col0 + n4 * 4);
            *(float4*)&b_s[kk][n4 * 4] = val;
        }
        __syncthreads();

#pragma unroll
        for (int kk = 0; kk < 16; kk++) {
            float av[TM], bv[TN];
#pragma unroll
            for (int i = 0; i < TM; i += 4)
                *(float4*)&av[i] = *(const float4*)&a_s[kk][tm * TM + i];
#pragma unroll
            for (int j = 0; j < TN; j += 4)
                *(float4*)&bv[j] = *(const float4*)&b_s[kk][tn * TN + j];
#pragma unroll
            for (int i = 0; i < TM; i++)
#pragma unroll
                for (int j = 0; j < TN; j++)
                    acc[i][j] = fmaf(av[i], bv[j], acc[i][j]);
        }
        __syncthreads();
    }

#pragma unroll
    for (int i = 0; i < TM; i++) {
        int row = row0 + tm * TM + i;
        float* dst = C + (size_t)row * N + col0 + tn * TN;
#pragma unroll
        for (int j = 0; j < TN; j += 4) {
            float4 bv = *(const float4*)(bias + col0 + tn * TN + j);
            float4 o;
            o.x = acc[i][j + 0] + bv.x;
            o.y = acc[i][j + 1] + bv.y;
            o.z = acc[i][j + 2] + bv.z;
            o.w = acc[i][j + 3] + bv.w;
            *(float4*)(dst + j) = o;
        }
    }
}

// ---------------------------------------------------------------------------
// Fused relative attention, 512 threads (8 waves -> 2/SIMD), reg-prefetch.
// score[q,k] = ( (q+u).K[k] + (q+v).R[j] ) / 8,  j = k + 1023 - q
// masked -1e30 where k > q + M_LEN; online softmax; PV accumulate.
// ---------------------------------------------------------------------------
__global__ __launch_bounds__(512)
void attn_fused(const float* __restrict__ w, const float* __restrict__ rproj,
                const float* __restrict__ u, const float* __restrict__ v,
                float* __restrict__ out) {
    __shared__ float qTu[64][68];   // [d][q]  (q+u) transposed
    __shared__ float qTv[64][68];   // [d][q]  (q+v) transposed
    __shared__ float ktT[64][68];   // [d][k]
    __shared__ float vt [64][68];   // [k][d]
    __shared__ float rtT[64][136];  // [d][t]  R window (128 rows)
    __shared__ float s1 [64][68];   // [q][k] ac-scores; later pT[k][q]
    __shared__ float s2 [64][136];  // [q][t] bd window scores
    __shared__ float alpha_s[64], l_s[64], m_s[64];

    const int qt  = blockIdx.x;
    const int hn  = blockIdx.y;
    const int b   = blockIdx.z;
    const int q0  = qt * 64;
    const int tid = threadIdx.x;
    const int tm  = tid >> 5;   // 0..15 : 4 q-rows
    const int tn  = tid & 31;   // 0..31 : 2 k-cols / 4 t-cols / 2 d-cols
    const int qr  = tid >> 3;   // 0..63 : softmax row
    const int kc  = tid & 7;    // 0..7  : softmax 8-col chunk

    // ---- prologue: stage (q+u),(q+v) transposed ----
#pragma unroll
    for (int it = 0; it < 2; ++it) {
        int idx = tid + it * 512;
        int dq = idx >> 4, d4 = idx & 15;
        const float* src = w + ((size_t)b * K_LEN + M_LEN + q0 + dq) * 1536 + hn * 64 + d4 * 4;
        float4 val = *(const float4*)src;
        float4 uu  = *(const float4*)(u + hn * 64 + d4 * 4);
        float4 vv  = *(const float4*)(v + hn * 64 + d4 * 4);
        qTu[d4 * 4 + 0][dq] = val.x + uu.x;
        qTu[d4 * 4 + 1][dq] = val.y + uu.y;
        qTu[d4 * 4 + 2][dq] = val.z + uu.z;
        qTu[d4 * 4 + 3][dq] = val.w + uu.w;
        qTv[d4 * 4 + 0][dq] = val.x + vv.x;
        qTv[d4 * 4 + 1][dq] = val.y + vv.y;
        qTv[d4 * 4 + 2][dq] = val.z + vv.z;
        qTv[d4 * 4 + 3][dq] = val.w + vv.w;
    }
    if (tid < 64) { m_s[tid] = -1e30f; l_s[tid] = 0.f; }

    float o[4][2];
#pragma unroll
    for (int i = 0; i < 4; i++) { o[i][0] = 0.f; o[i][1] = 0.f; }

    const int ntiles = qt + 17;

    // ---- prefetch tile 0 into registers ----
    float4 kreg[2], vreg[2], rreg[4];
    {
        const int jb = 960 - q0;
#pragma unroll
        for (int it = 0; it < 2; ++it) {
            int idx = tid + it * 512;
            int kk = idx >> 4, d4 = idx & 15;
            const float* base = w + ((size_t)b * K_LEN + kk) * 1536 + hn * 64 + d4 * 4;
            kreg[it] = *(const float4*)(base + 512);
            vreg[it] = *(const float4*)(base + 1024);
        }
#pragma unroll
        for (int it = 0; it < 4; ++it) {
            int idx = tid + it * 512;
            int t = idx >> 4, d4 = idx & 15;
            int j = jb + t; j = j < 2047 ? j : 2047;
            rreg[it] = *(const float4*)(rproj + (size_t)j * 512 + hn * 64 + d4 * 4);
        }
    }

    for (int ti = 0; ti < ntiles; ++ti) {
        const int k0 = ti * 64;
        __syncthreads();   // previous tile fully consumed

        // ---- write staged regs -> LDS ----
#pragma unroll
        for (int it = 0; it < 2; ++it) {
            int idx = tid + it * 512;
            int kk = idx >> 4, d4 = idx & 15;
            ktT[d4 * 4 + 0][kk] = kreg[it].x;
            ktT[d4 * 4 + 1][kk] = kreg[it].y;
            ktT[d4 * 4 + 2][kk] = kreg[it].z;
            ktT[d4 * 4 + 3][kk] = kreg[it].w;
            *(float4*)&vt[kk][d4 * 4] = vreg[it];
        }
#pragma unroll
        for (int it = 0; it < 4; ++it) {
            int idx = tid + it * 512;
            int t = idx >> 4, d4 = idx & 15;
            rtT[d4 * 4 + 0][t] = rreg[it].x;
            rtT[d4 * 4 + 1][t] = rreg[it].y;
            rtT[d4 * 4 + 2][t] = rreg[it].z;
            rtT[d4 * 4 + 3][t] = rreg[it].w;
        }

        // ---- prefetch tile ti+1 (latency hides under GEMM) ----
        if (ti + 1 < ntiles) {
            const int k0n = k0 + 64;
            const int jbn = k0n + 960 - q0;
#pragma unroll
            for (int it = 0; it < 2; ++it) {
                int idx = tid + it * 512;
                int kk = idx >> 4, d4 = idx & 15;
                const float* base = w + ((size_t)b * K_LEN + k0n + kk) * 1536 + hn * 64 + d4 * 4;
                kreg[it] = *(const float4*)(base + 512);
                vreg[it] = *(const float4*)(base + 1024);
            }
#pragma unroll
            for (int it = 0; it < 4; ++it) {
                int idx = tid + it * 512;
                int t = idx >> 4, d4 = idx & 15;
                int j = jbn + t; j = j < 2047 ? j : 2047;
                rreg[it] = *(const float4*)(rproj + (size_t)j * 512 + hn * 64 + d4 * 4);
            }
        }
        __syncthreads();

        // ---- S1 = (q+u)^T.K : acc1[4q][2k] ----
        float acc1[4][2];
#pragma unroll
        for (int i = 0; i < 4; i++) { acc1[i][0] = 0.f; acc1[i][1] = 0.f; }
#pragma unroll 8
        for (int d = 0; d < 64; ++d) {
            float4 av = *(const float4*)&qTu[d][tm * 4];
            float2 bk = *(const float2*)&ktT[d][tn * 2];
            acc1[0][0] = fmaf(av.x, bk.x, acc1[0][0]);
            acc1[0][1] = fmaf(av.x, bk.y, acc1[0][1]);
            acc1[1][0] = fmaf(av.y, bk.x, acc1[1][0]);
            acc1[1][1] = fmaf(av.y, bk.y, acc1[1][1]);
            acc1[2][0] = fmaf(av.z, bk.x, acc1[2][0]);
            acc1[2][1] = fmaf(av.z, bk.y, acc1[2][1]);
            acc1[3][0] = fmaf(av.w, bk.x, acc1[3][0]);
            acc1[3][1] = fmaf(av.w, bk.y, acc1[3][1]);
        }
        // ---- S2 = (q+v)^T.Rwin : acc2[4q][4t] ----
        float acc2[4][4];
#pragma unroll
        for (int i = 0; i < 4; i++)
#pragma unroll
            for (int j = 0; j < 4; j++) acc2[i][j] = 0.f;
#pragma unroll 8
        for (int d = 0; d < 64; ++d) {
            float4 av = *(const float4*)&qTv[d][tm * 4];
            float4 br = *(const float4*)&rtT[d][tn * 4];
            float avv[4] = {av.x, av.y, av.z, av.w};
            float brv[4] = {br.x, br.y, br.z, br.w};
#pragma unroll
            for (int i = 0; i < 4; i++)
#pragma unroll
                for (int j = 0; j < 4; j++)
                    acc2[i][j] = fmaf(avv[i], brv[j], acc2[i][j]);
        }
#pragma unroll
        for (int i = 0; i < 4; i++) {
            float2 st1; st1.x = acc1[i][0]; st1.y = acc1[i][1];
            *(float2*)&s1[tm * 4 + i][tn * 2] = st1;
            float4 st2; st2.x = acc2[i][0]; st2.y = acc2[i][1];
            st2.z = acc2[i][2]; st2.w = acc2[i][3];
            *(float4*)&s2[tm * 4 + i][tn * 4] = st2;
        }
        __syncthreads();

        // ---- online softmax: 8 lanes per q-row ----
        float p[8];
        float mloc = -1e30f;
        const int q = q0 + qr;
        float s1v[8];
        *(float4*)&s1v[0] = *(const float4*)&s1[qr][kc * 8];
        *(float4*)&s1v[4] = *(const float4*)&s1[qr][kc * 8 + 4];
#pragma unroll
        for (int i = 0; i < 8; ++i) {
            int dk = kc * 8 + i;
            int t  = dk + 63 - qr;          // 0..126
            float x = (s1v[i] + s2[qr][t]) * 0.125f;
            if (k0 + dk > q + M_LEN) x = -1e30f;
            p[i] = x;
            mloc = fmaxf(mloc, x);
        }
        mloc = fmaxf(mloc, __shfl_xor(mloc, 1));
        mloc = fmaxf(mloc, __shfl_xor(mloc, 2));
        mloc = fmaxf(mloc, __shfl_xor(mloc, 4));
        float mold = m_s[qr];
        float mnew = fmaxf(mold, mloc);
        float alpha = __expf(mold - mnew);
        float lsum = 0.f;
#pragma unroll
        for (int i = 0; i < 8; ++i) {
            float pe = __expf(p[i] - mnew);
            p[i] = pe;
            lsum += pe;
        }
        lsum += __shfl_xor(lsum, 1);
        lsum += __shfl_xor(lsum, 2);
        lsum += __shfl_xor(lsum, 4);
        if (kc == 0) {
            m_s[qr]     = mnew;
            l_s[qr]     = l_s[qr] * alpha + lsum;
            alpha_s[qr] = alpha;
        }
        __syncthreads();   // all reads of s1/s2 done

        // write P transposed: pT[k][q] into s1
#pragma unroll
        for (int i = 0; i < 8; ++i) s1[kc * 8 + i][qr] = p[i];
        __syncthreads();

        // ---- PV: o[4q][2d] += pT . V ----
#pragma unroll
        for (int i = 0; i < 4; i++) {
            float a = alpha_s[tm * 4 + i];
            o[i][0] *= a; o[i][1] *= a;
        }
#pragma unroll 8
        for (int k = 0; k < 64; ++k) {
            float4 av = *(const float4*)&s1[k][tm * 4];
            float2 bv = *(const float2*)&vt[k][tn * 2];
            o[0][0] = fmaf(av.x, bv.x, o[0][0]);
            o[0][1] = fmaf(av.x, bv.y, o[0][1]);
            o[1][0] = fmaf(av.y, bv.x, o[1][0]);
            o[1][1] = fmaf(av.y, bv.y, o[1][1]);
            o[2][0] = fmaf(av.z, bv.x, o[2][0]);
            o[2][1] = fmaf(av.z, bv.y, o[2][1]);
            o[3][0] = fmaf(av.w, bv.x, o[3][0]);
            o[3][1] = fmaf(av.w, bv.y, o[3][1]);
        }
    }

    // ---- epilogue: normalize, store (b,q,n,d) ----
    __syncthreads();
#pragma unroll
    for (int i = 0; i < 4; i++) {
        float inv = 1.f / l_s[tm * 4 + i];
        float2 ov;
        ov.x = o[i][0] * inv;
        ov.y = o[i][1] * inv;
        float* dst = out + (((size_t)b * Q_LEN + q0 + tm * 4 + i) * N_HEADS + hn) * D_K + tn * 2;
        *(float2*)dst = ov;
    }
}

// ---------------------------------------------------------------------------
extern "C" void kernel_launch(void* const* d_in, const int* in_sizes, int n_in,
                              void* d_out, int out_size, void* d_ws, size_t ws_size,
                              hipStream_t stream) {
    (void)in_sizes; (void)n_in; (void)out_size; (void)ws_size;

    const float* inputs = (const float*)d_in[0];
    const float* mem    = (const float*)d_in[1];
    const float* r      = (const float*)d_in[2];
    const float* Wqkv   = (const float*)d_in[3];
    const float* bqkv   = (const float*)d_in[4];
    const float* Wr     = (const float*)d_in[5];
    const float* br     = (const float*)d_in[6];
    const float* Wo     = (const float*)d_in[7];
    const float* bo     = (const float*)d_in[8];
    const float* u      = (const float*)d_in[9];
    const float* v      = (const float*)d_in[10];
    float* out = (float*)d_out;

    float* w     = (float*)d_ws;                   // 8192 x 1536
    float* rproj = w + (size_t)8192 * 1536;        // 2048 x 512
    float* attn  = rproj + (size_t)2048 * 512;     // 4096 x 512 (b,q,n,d)

    hipLaunchKernelGGL((gemm_bias<128, 128, 8, 8>), dim3(64, 12), dim3(256), 0, stream,
                       mem, inputs, Wqkv, bqkv, w, 1536, 512, 0);
    hipLaunchKernelGGL((gemm_bias<64, 64, 4, 4>), dim3(32, 8), dim3(256), 0, stream,
                       r, r, Wr, br, rproj, 512, 512, 1);
    hipLaunchKernelGGL(attn_fused, dim3(16, 8, 4), dim3(512), 0, stream,
                       w, rproj, u, v, attn);
    hipLaunchKernelGGL((gemm_bias<64, 64, 4, 4>), dim3(64, 8), dim3(256), 0, stream,
                       attn, attn, Wo, bo, out, 512, 512, 1);
}

// Round 4
// 748.489 us; speedup vs baseline: 1.4670x; 1.4169x over previous
//
#include <hip/hip_runtime.h>

#define D_MODEL 512
#define N_HEADS 8
#define D_K     64
#define BATCH   4
#define Q_LEN   1024
#define M_LEN   1024
#define K_LEN   2048

typedef short bf16x8 __attribute__((ext_vector_type(8)));
typedef float f32x4  __attribute__((ext_vector_type(4)));

__device__ __forceinline__ unsigned short bf16_rne(float x) {
    unsigned int u = __float_as_uint(x);
    return (unsigned short)((u + 0x7FFFu + ((u >> 16) & 1u)) >> 16);
}
__device__ __forceinline__ float bf16_tof(unsigned short h) {
    return __uint_as_float(((unsigned int)h) << 16);
}
__device__ __forceinline__ void split4(float4 x, ushort4& h, ushort4& l) {
    h.x = bf16_rne(x.x); h.y = bf16_rne(x.y);
    h.z = bf16_rne(x.z); h.w = bf16_rne(x.w);
    l.x = bf16_rne(x.x - bf16_tof(h.x));
    l.y = bf16_rne(x.y - bf16_tof(h.y));
    l.z = bf16_rne(x.z - bf16_tof(h.z));
    l.w = bf16_rne(x.w - bf16_tof(h.w));
}

// ---------------------------------------------------------------------------
// Generic fp32 tiled GEMM (unchanged): C = A*B + bias
// ---------------------------------------------------------------------------
template<int BM, int BN, int TM, int TN>
__global__ __launch_bounds__(256)
void gemm_bias(const float* __restrict__ a0, const float* __restrict__ a1,
               const float* __restrict__ B, const float* __restrict__ bias,
               float* __restrict__ C, int N, int K, int mode) {
    __shared__ float a_s[16][BM + 4];
    __shared__ float b_s[16][BN + 4];

    const int tid  = threadIdx.x;
    const int row0 = blockIdx.x * BM;
    const int col0 = blockIdx.y * BN;
    const int tm   = tid / (BN / TN);
    const int tn   = tid % (BN / TN);

    float acc[TM][TN];
#pragma unroll
    for (int i = 0; i < TM; i++)
#pragma unroll
        for (int j = 0; j < TN; j++) acc[i][j] = 0.f;

    for (int k0 = 0; k0 < K; k0 += 16) {
        for (int idx = tid; idx < BM * 4; idx += 256) {
            int m  = idx >> 2;
            int k4 = idx & 3;
            int row = row0 + m;
            const float* src;
            if (mode == 0) {
                int b = row >> 11;
                int t = row & 2047;
                src = (t < M_LEN) ? (a0 + ((size_t)b * M_LEN + t) * K)
                                  : (a1 + ((size_t)b * Q_LEN + (t - M_LEN)) * K);
            } else {
                src = a0 + (size_t)row * K;
            }
            float4 val = *(const float4*)(src + k0 + k4 * 4);
            a_s[k4 * 4 + 0][m] = val.x;
            a_s[k4 * 4 + 1][m] = val.y;
            a_s[k4 * 4 + 2][m] = val.z;
            a_s[k4 * 4 + 3][m] = val.w;
        }
        for (int idx = tid; idx < BN * 4; idx += 256) {
            int kk = idx / (BN / 4);
            int n4 = idx % (BN / 4);
            float4 val = *(const float4*)(B + (size_t)(k0 + kk) * N + col0 + n4 * 4);
            *(float4*)&b_s[kk][n4 * 4] = val;
        }
        __syncthreads();

#pragma unroll
        for (int kk = 0; kk < 16; kk++) {
            float av[TM], bv[TN];
#pragma unroll
            for (int i = 0; i < TM; i += 4)
                *(float4*)&av[i] = *(const float4*)&a_s[kk][tm * TM + i];
#pragma unroll
            for (int j = 0; j < TN; j += 4)
                *(float4*)&bv[j] = *(const float4*)&b_s[kk][tn * TN + j];
#pragma unroll
            for (int i = 0; i < TM; i++)
#pragma unroll
                for (int j = 0; j < TN; j++)
                    acc[i][j] = fmaf(av[i], bv[j], acc[i][j]);
        }
        __syncthreads();
    }

#pragma unroll
    for (int i = 0; i < TM; i++) {
        int row = row0 + tm * TM + i;
        float* dst = C + (size_t)row * N + col0 + tn * TN;
#pragma unroll
        for (int j = 0; j < TN; j += 4) {
            float4 bv = *(const float4*)(bias + col0 + tn * TN + j);
            float4 o;
            o.x = acc[i][j + 0] + bv.x;
            o.y = acc[i][j + 1] + bv.y;
            o.z = acc[i][j + 2] + bv.z;
            o.w = acc[i][j + 3] + bv.w;
            *(float4*)(dst + j) = o;
        }
    }
}

// ---------------------------------------------------------------------------
// Fused relative attention. 512 thr = 8 waves.
// S1 = (q+u).K^T and S2 = (q+u).Rwin^T via split-bf16 MFMA 16x16x32 (fp32 acc).
// bd correction: vc[t] = (v-u).R[t] (fp32). Softmax + PV remain fp32.
// R window = circular 128-row buffer (64 new rows/iter).
// score[q,k] = (S1 + S2[t] + vc[t]) / 8,  t = k-k0 + 63 - (q-q0)
// ---------------------------------------------------------------------------
__global__ __launch_bounds__(512)
void attn_fused(const float* __restrict__ w, const float* __restrict__ rproj,
                const float* __restrict__ u, const float* __restrict__ v,
                float* __restrict__ out) {
    __shared__ unsigned short quh[64][72], qul[64][72];   // (q+u) hi/lo  [q][d]
    __shared__ unsigned short kh_[64][72], kl_[64][72];   // K hi/lo      [k][d]
    __shared__ unsigned short rh_[128][72], rl_[128][72]; // R circ hi/lo [slot][d]
    __shared__ float vt [64][68];                         // V fp32       [k][d]
    __shared__ float s1f[64][68];                         // S1 scores; reused as pT[k][q]
    __shared__ float s2f[64][132];                        // S2 window scores [q][t]
    __shared__ float vc [128];                            // (v-u).R per slot
    __shared__ float uvd[64];
    __shared__ float alpha_s[64], l_s[64], m_s[64];

    const int qt  = blockIdx.x;
    const int hn  = blockIdx.y;
    const int b   = blockIdx.z;
    const int q0  = qt * 64;
    const int tid = threadIdx.x;

    const int wv = tid >> 6, ln = tid & 63;
    const int lr = ln & 15, lg = ln >> 4;     // MFMA frag row/col, k-group
    const int qi = wv & 3,  g2 = wv >> 2;     // wave tile assignment
    const int qr = tid >> 3, kc = tid & 7;    // softmax mapping
    const int tm = tid >> 5, tn = tid & 31;   // PV mapping

    // ---- prologue: stage (q+u) split hi/lo; uvd; init m/l ----
#pragma unroll
    for (int it = 0; it < 2; ++it) {
        int idx = tid + it * 512;
        int dq = idx >> 4, d4 = idx & 15;
        const float* src = w + ((size_t)b * K_LEN + M_LEN + q0 + dq) * 1536 + hn * 64 + d4 * 4;
        float4 val = *(const float4*)src;
        float4 uu  = *(const float4*)(u + hn * 64 + d4 * 4);
        val.x += uu.x; val.y += uu.y; val.z += uu.z; val.w += uu.w;
        ushort4 h, l;
        split4(val, h, l);
        *(ushort4*)&quh[dq][d4 * 4] = h;
        *(ushort4*)&qul[dq][d4 * 4] = l;
    }
    if (tid < 64) {
        uvd[tid] = v[hn * 64 + tid] - u[hn * 64 + tid];
        m_s[tid] = -1e30f;
        l_s[tid] = 0.f;
    }

    float o[4][2];
#pragma unroll
    for (int i = 0; i < 4; i++) { o[i][0] = 0.f; o[i][1] = 0.f; }

    const int ntiles = qt + 17;

    // ---- prefetch tile 0: K/V rows [0,64), R rows [jb0, jb0+128) ----
    float4 kreg[2], vreg[2], rreg[4];
    {
        const int jb0 = 960 - q0;
#pragma unroll
        for (int it = 0; it < 2; ++it) {
            int idx = tid + it * 512;
            int kk = idx >> 4, d4 = idx & 15;
            const float* base = w + ((size_t)b * K_LEN + kk) * 1536 + hn * 64 + d4 * 4;
            kreg[it] = *(const float4*)(base + 512);
            vreg[it] = *(const float4*)(base + 1024);
        }
#pragma unroll
        for (int it = 0; it < 4; ++it) {
            int idx = tid + it * 512;
            int s = idx >> 4, d4 = idx & 15;
            int j = jb0 + s; j = j < 2047 ? j : 2047;
            rreg[it] = *(const float4*)(rproj + (size_t)j * 512 + hn * 64 + d4 * 4);
        }
    }

    for (int ti = 0; ti < ntiles; ++ti) {
        const int k0 = ti * 64;
        const int jb = k0 + 960 - q0;
        __syncthreads();   // previous tile fully consumed

        // ---- stage K (split bf16), V (fp32) ----
#pragma unroll
        for (int it = 0; it < 2; ++it) {
            int idx = tid + it * 512;
            int kk = idx >> 4, d4 = idx & 15;
            ushort4 h, l;
            split4(kreg[it], h, l);
            *(ushort4*)&kh_[kk][d4 * 4] = h;
            *(ushort4*)&kl_[kk][d4 * 4] = l;
            *(float4*)&vt[kk][d4 * 4] = vreg[it];
        }
        // ---- stage R rows into circular buffer ----
        {
            int rn    = (ti == 0) ? 4 : 2;
            int rbase = (ti == 0) ? jb : jb + 64;
            for (int it = 0; it < rn; ++it) {
                int idx = tid + it * 512;
                int s = idx >> 4, d4 = idx & 15;
                int slot = (rbase + s) & 127;
                ushort4 h, l;
                split4(rreg[it], h, l);
                *(ushort4*)&rh_[slot][d4 * 4] = h;
                *(ushort4*)&rl_[slot][d4 * 4] = l;
            }
        }
        // ---- prefetch next tile ----
        if (ti + 1 < ntiles) {
            int k0n = k0 + 64;
#pragma unroll
            for (int it = 0; it < 2; ++it) {
                int idx = tid + it * 512;
                int kk = idx >> 4, d4 = idx & 15;
                const float* base = w + ((size_t)b * K_LEN + k0n + kk) * 1536 + hn * 64 + d4 * 4;
                kreg[it] = *(const float4*)(base + 512);
                vreg[it] = *(const float4*)(base + 1024);
            }
#pragma unroll
            for (int it = 0; it < 2; ++it) {
                int idx = tid + it * 512;
                int s = idx >> 4, d4 = idx & 15;
                int j = jb + 128 + s; j = j < 2047 ? j : 2047;
                rreg[it] = *(const float4*)(rproj + (size_t)j * 512 + hn * 64 + d4 * 4);
            }
        }
        __syncthreads();   // staged tiles visible

        // ---- vc[t] = (v-u).R for new slots (wave 0/1, overlaps MFMA) ----
        {
            int nvc   = (ti == 0) ? 128 : 64;
            int vbase = (ti == 0) ? jb : jb + 64;
            if (tid < nvc) {
                int slot = (vbase + tid) & 127;
                float s = 0.f;
#pragma unroll 8
                for (int d = 0; d < 64; ++d) {
                    float rv = bf16_tof(rh_[slot][d]) + bf16_tof(rl_[slot][d]);
                    s = fmaf(uvd[d], rv, s);
                }
                vc[slot] = s;
            }
        }

        // ---- MFMA: S1 (2 tiles/wave), S2 (4 tiles/wave), split-bf16 ----
        {
            f32x4 c1[2] = {{0.f,0.f,0.f,0.f},{0.f,0.f,0.f,0.f}};
            f32x4 c2[4] = {{0.f,0.f,0.f,0.f},{0.f,0.f,0.f,0.f},
                           {0.f,0.f,0.f,0.f},{0.f,0.f,0.f,0.f}};
#pragma unroll
            for (int ks = 0; ks < 2; ++ks) {
                const int dof = ks * 32 + lg * 8;
                bf16x8 ah = *(const bf16x8*)&quh[qi * 16 + lr][dof];
                bf16x8 al = *(const bf16x8*)&qul[qi * 16 + lr][dof];
#pragma unroll
                for (int t = 0; t < 2; ++t) {
                    int krow = (g2 * 2 + t) * 16 + lr;
                    bf16x8 bh = *(const bf16x8*)&kh_[krow][dof];
                    bf16x8 bl = *(const bf16x8*)&kl_[krow][dof];
                    c1[t] = __builtin_amdgcn_mfma_f32_16x16x32_bf16(ah, bh, c1[t], 0, 0, 0);
                    c1[t] = __builtin_amdgcn_mfma_f32_16x16x32_bf16(ah, bl, c1[t], 0, 0, 0);
                    c1[t] = __builtin_amdgcn_mfma_f32_16x16x32_bf16(al, bh, c1[t], 0, 0, 0);
                }
#pragma unroll
                for (int t = 0; t < 4; ++t) {
                    int slot = (jb + (g2 * 4 + t) * 16 + lr) & 127;
                    bf16x8 bh = *(const bf16x8*)&rh_[slot][dof];
                    bf16x8 bl = *(const bf16x8*)&rl_[slot][dof];
                    c2[t] = __builtin_amdgcn_mfma_f32_16x16x32_bf16(ah, bh, c2[t], 0, 0, 0);
                    c2[t] = __builtin_amdgcn_mfma_f32_16x16x32_bf16(ah, bl, c2[t], 0, 0, 0);
                    c2[t] = __builtin_amdgcn_mfma_f32_16x16x32_bf16(al, bh, c2[t], 0, 0, 0);
                }
            }
            // C/D layout: col = lane&15, row = (lane>>4)*4 + reg
#pragma unroll
            for (int t = 0; t < 2; ++t)
#pragma unroll
                for (int r = 0; r < 4; ++r)
                    s1f[qi * 16 + lg * 4 + r][(g2 * 2 + t) * 16 + lr] = c1[t][r];
#pragma unroll
            for (int t = 0; t < 4; ++t)
#pragma unroll
                for (int r = 0; r < 4; ++r)
                    s2f[qi * 16 + lg * 4 + r][(g2 * 4 + t) * 16 + lr] = c2[t][r];
        }
        __syncthreads();   // scores + vc ready

        // ---- online softmax: 8 lanes per q-row ----
        float p[8];
        float mloc = -1e30f;
        const int q = q0 + qr;
        float s1v[8];
        *(float4*)&s1v[0] = *(const float4*)&s1f[qr][kc * 8];
        *(float4*)&s1v[4] = *(const float4*)&s1f[qr][kc * 8 + 4];
#pragma unroll
        for (int i = 0; i < 8; ++i) {
            int dk = kc * 8 + i;
            int t  = dk + 63 - qr;          // 0..126
            float x = (s1v[i] + s2f[qr][t] + vc[(jb + t) & 127]) * 0.125f;
            if (k0 + dk > q + M_LEN) x = -1e30f;
            p[i] = x;
            mloc = fmaxf(mloc, x);
        }
        mloc = fmaxf(mloc, __shfl_xor(mloc, 1));
        mloc = fmaxf(mloc, __shfl_xor(mloc, 2));
        mloc = fmaxf(mloc, __shfl_xor(mloc, 4));
        float mold = m_s[qr];
        float mnew = fmaxf(mold, mloc);
        float alpha = __expf(mold - mnew);
        float lsum = 0.f;
#pragma unroll
        for (int i = 0; i < 8; ++i) {
            float pe = __expf(p[i] - mnew);
            p[i] = pe;
            lsum += pe;
        }
        lsum += __shfl_xor(lsum, 1);
        lsum += __shfl_xor(lsum, 2);
        lsum += __shfl_xor(lsum, 4);
        if (kc == 0) {
            m_s[qr]     = mnew;
            l_s[qr]     = l_s[qr] * alpha + lsum;
            alpha_s[qr] = alpha;
        }
        __syncthreads();   // all reads of s1f/s2f done

        // write P transposed: pT[k][q] into s1f buffer
#pragma unroll
        for (int i = 0; i < 8; ++i) s1f[kc * 8 + i][qr] = p[i];
        __syncthreads();

        // ---- PV (fp32): o[4q][2d] += pT . V ----
#pragma unroll
        for (int i = 0; i < 4; i++) {
            float a = alpha_s[tm * 4 + i];
            o[i][0] *= a; o[i][1] *= a;
        }
#pragma unroll 8
        for (int k = 0; k < 64; ++k) {
            float4 av = *(const float4*)&s1f[k][tm * 4];
            float2 bv = *(const float2*)&vt[k][tn * 2];
            o[0][0] = fmaf(av.x, bv.x, o[0][0]);
            o[0][1] = fmaf(av.x, bv.y, o[0][1]);
            o[1][0] = fmaf(av.y, bv.x, o[1][0]);
            o[1][1] = fmaf(av.y, bv.y, o[1][1]);
            o[2][0] = fmaf(av.z, bv.x, o[2][0]);
            o[2][1] = fmaf(av.z, bv.y, o[2][1]);
            o[3][0] = fmaf(av.w, bv.x, o[3][0]);
            o[3][1] = fmaf(av.w, bv.y, o[3][1]);
        }
    }

    // ---- epilogue: normalize, store (b,q,n,d) ----
    __syncthreads();
#pragma unroll
    for (int i = 0; i < 4; i++) {
        float inv = 1.f / l_s[tm * 4 + i];
        float2 ov;
        ov.x = o[i][0] * inv;
        ov.y = o[i][1] * inv;
        float* dst = out + (((size_t)b * Q_LEN + q0 + tm * 4 + i) * N_HEADS + hn) * D_K + tn * 2;
        *(float2*)dst = ov;
    }
}

// ---------------------------------------------------------------------------
extern "C" void kernel_launch(void* const* d_in, const int* in_sizes, int n_in,
                              void* d_out, int out_size, void* d_ws, size_t ws_size,
                              hipStream_t stream) {
    (void)in_sizes; (void)n_in; (void)out_size; (void)ws_size;

    const float* inputs = (const float*)d_in[0];
    const float* mem    = (const float*)d_in[1];
    const float* r      = (const float*)d_in[2];
    const float* Wqkv   = (const float*)d_in[3];
    const float* bqkv   = (const float*)d_in[4];
    const float* Wr     = (const float*)d_in[5];
    const float* br     = (const float*)d_in[6];
    const float* Wo     = (const float*)d_in[7];
    const float* bo     = (const float*)d_in[8];
    const float* u      = (const float*)d_in[9];
    const float* v      = (const float*)d_in[10];
    float* out = (float*)d_out;

    float* w     = (float*)d_ws;                   // 8192 x 1536
    float* rproj = w + (size_t)8192 * 1536;        // 2048 x 512
    float* attn  = rproj + (size_t)2048 * 512;     // 4096 x 512 (b,q,n,d)

    hipLaunchKernelGGL((gemm_bias<128, 128, 8, 8>), dim3(64, 12), dim3(256), 0, stream,
                       mem, inputs, Wqkv, bqkv, w, 1536, 512, 0);
    hipLaunchKernelGGL((gemm_bias<64, 64, 4, 4>), dim3(32, 8), dim3(256), 0, stream,
                       r, r, Wr, br, rproj, 512, 512, 1);
    hipLaunchKernelGGL(attn_fused, dim3(16, 8, 4), dim3(512), 0, stream,
                       w, rproj, u, v, attn);
    hipLaunchKernelGGL((gemm_bias<64, 64, 4, 4>), dim3(64, 8), dim3(256), 0, stream,
                       attn, attn, Wo, bo, out, 512, 512, 1);
}

// Round 5
// 527.847 us; speedup vs baseline: 2.0801x; 1.4180x over previous
//
#include <hip/hip_runtime.h>

#define D_MODEL 512
#define N_HEADS 8
#define D_K     64
#define BATCH   4
#define Q_LEN   1024
#define M_LEN   1024
#define K_LEN   2048

typedef short bf16x8 __attribute__((ext_vector_type(8)));
typedef float f32x4  __attribute__((ext_vector_type(4)));

__device__ __forceinline__ unsigned short bf16_rne(float x) {
    unsigned int u = __float_as_uint(x);
    return (unsigned short)((u + 0x7FFFu + ((u >> 16) & 1u)) >> 16);
}
__device__ __forceinline__ float bf16_tof(unsigned short h) {
    return __uint_as_float(((unsigned int)h) << 16);
}
__device__ __forceinline__ void split4(float4 x, ushort4& h, ushort4& l) {
    h.x = bf16_rne(x.x); h.y = bf16_rne(x.y);
    h.z = bf16_rne(x.z); h.w = bf16_rne(x.w);
    l.x = bf16_rne(x.x - bf16_tof(h.x));
    l.y = bf16_rne(x.y - bf16_tof(h.y));
    l.z = bf16_rne(x.z - bf16_tof(h.z));
    l.w = bf16_rne(x.w - bf16_tof(h.w));
}

// ---------------------------------------------------------------------------
// prep_w: W[512][N] (fp32) -> W^T hi/lo bf16 [N][512]. Tile-transpose via LDS
// so both global sides are coalesced. grid (N/64, 8), 256 thr.
// ---------------------------------------------------------------------------
__global__ __launch_bounds__(256)
void prep_w(const float* __restrict__ W, unsigned short* __restrict__ oh,
            unsigned short* __restrict__ ol, int N) {
    __shared__ float t[64][65];
    const int tid = threadIdx.x;
    const int nb = blockIdx.x * 64, kb = blockIdx.y * 64;
#pragma unroll
    for (int i = 0; i < 4; ++i) {
        int idx = tid + i * 256;
        int k = idx >> 4, n4 = idx & 15;
        float4 v = *(const float4*)(W + (size_t)(kb + k) * N + nb + n4 * 4);
        t[n4 * 4 + 0][k] = v.x;
        t[n4 * 4 + 1][k] = v.y;
        t[n4 * 4 + 2][k] = v.z;
        t[n4 * 4 + 3][k] = v.w;
    }
    __syncthreads();
    int n = tid >> 2, kq = (tid & 3) * 16;
    unsigned short hbuf[16], lbuf[16];
#pragma unroll
    for (int j = 0; j < 16; ++j) {
        float f = t[n][kq + j];
        unsigned short h = bf16_rne(f);
        hbuf[j] = h;
        lbuf[j] = bf16_rne(f - bf16_tof(h));
    }
    size_t base = (size_t)(nb + n) * 512 + kb + kq;
#pragma unroll
    for (int j = 0; j < 16; j += 4) {
        *(ushort4*)(oh + base + j) = *(ushort4*)&hbuf[j];
        *(ushort4*)(ol + base + j) = *(ushort4*)&lbuf[j];
    }
}

// ---------------------------------------------------------------------------
// Split-bf16 MFMA GEMM: C[M][N] = A[M][512] * B[512][N] + bias, fp32 I/O.
// B pre-transposed/split (bth/btl = B^T [N][512]). 128x128 tile, BK=32,
// 256 thr = 4 waves (2x2), 16 16x16 subtiles/wave, 3 MFMA per product.
// mode 0: A rows = concat(mem, inputs) per batch. mode 1: plain.
// ---------------------------------------------------------------------------
__global__ __launch_bounds__(256, 2)
void gemm_mfma(const float* __restrict__ a0, const float* __restrict__ a1,
               const unsigned short* __restrict__ bth,
               const unsigned short* __restrict__ btl,
               const float* __restrict__ bias, float* __restrict__ C,
               int N, int mode) {
    __shared__ unsigned short ah[128][40], al[128][40];
    __shared__ unsigned short bh[128][40], bl[128][40];
    const int tid  = threadIdx.x;
    const int row0 = blockIdx.x * 128, col0 = blockIdx.y * 128;
    const int ln = tid & 63, lr = ln & 15, lg = ln >> 4;
    const int wv = tid >> 6;
    const int ms = (wv & 1) * 64, ns = (wv >> 1) * 64;

    f32x4 c[4][4];
#pragma unroll
    for (int i = 0; i < 4; ++i)
#pragma unroll
        for (int j = 0; j < 4; ++j) c[i][j] = (f32x4){0.f, 0.f, 0.f, 0.f};

    for (int k0 = 0; k0 < 512; k0 += 32) {
        // stage A (fp32 -> split bf16), coalesced
#pragma unroll
        for (int i = 0; i < 4; ++i) {
            int idx = tid + i * 256;
            int m = idx >> 3, k4 = idx & 7;
            int row = row0 + m;
            const float* src;
            if (mode == 0) {
                int b = row >> 11, t = row & 2047;
                src = (t < M_LEN) ? (a0 + ((size_t)b * M_LEN + t) * 512)
                                  : (a1 + ((size_t)b * Q_LEN + (t - M_LEN)) * 512);
            } else {
                src = a0 + (size_t)row * 512;
            }
            float4 v = *(const float4*)(src + k0 + k4 * 4);
            ushort4 h, l;
            split4(v, h, l);
            *(ushort4*)&ah[m][k4 * 4] = h;
            *(ushort4*)&al[m][k4 * 4] = l;
        }
        // stage B (pre-split, plain 16B copies)
#pragma unroll
        for (int i = 0; i < 2; ++i) {
            int idx = tid + i * 256;
            int n = idx >> 2, kq = (idx & 3) * 8;
            size_t g = (size_t)(col0 + n) * 512 + k0 + kq;
            *(uint4*)&bh[n][kq] = *(const uint4*)(bth + g);
            *(uint4*)&bl[n][kq] = *(const uint4*)(btl + g);
        }
        __syncthreads();

        bf16x8 af_h[4], af_l[4], bf_h[4], bf_l[4];
#pragma unroll
        for (int i = 0; i < 4; ++i) {
            af_h[i] = *(const bf16x8*)&ah[ms + i * 16 + lr][lg * 8];
            af_l[i] = *(const bf16x8*)&al[ms + i * 16 + lr][lg * 8];
            bf_h[i] = *(const bf16x8*)&bh[ns + i * 16 + lr][lg * 8];
            bf_l[i] = *(const bf16x8*)&bl[ns + i * 16 + lr][lg * 8];
        }
#pragma unroll
        for (int i = 0; i < 4; ++i)
#pragma unroll
            for (int j = 0; j < 4; ++j) {
                c[i][j] = __builtin_amdgcn_mfma_f32_16x16x32_bf16(af_h[i], bf_h[j], c[i][j], 0, 0, 0);
                c[i][j] = __builtin_amdgcn_mfma_f32_16x16x32_bf16(af_h[i], bf_l[j], c[i][j], 0, 0, 0);
                c[i][j] = __builtin_amdgcn_mfma_f32_16x16x32_bf16(af_l[i], bf_h[j], c[i][j], 0, 0, 0);
            }
        __syncthreads();
    }

    // epilogue: C/D layout col=lane&15, row=(lane>>4)*4+reg
#pragma unroll
    for (int i = 0; i < 4; ++i) {
        int rbase = row0 + ms + i * 16 + lg * 4;
#pragma unroll
        for (int j = 0; j < 4; ++j) {
            int col = col0 + ns + j * 16 + lr;
            float bv = bias[col];
#pragma unroll
            for (int r = 0; r < 4; ++r)
                C[(size_t)(rbase + r) * N + col] = c[i][j][r] + bv;
        }
    }
}

// ---------------------------------------------------------------------------
// Fused relative attention, fully MFMA (S1, S2, PV split-bf16; softmax fp32).
// 512 thr = 8 waves. score[q,k] = (S1 + S2[t] + vc[t])/8, t = k-k0+63-(q-q0).
// ---------------------------------------------------------------------------
__global__ __launch_bounds__(512)
void attn_fused(const float* __restrict__ w, const float* __restrict__ rproj,
                const float* __restrict__ u, const float* __restrict__ v,
                float* __restrict__ out) {
    __shared__ unsigned short quh[64][72], qul[64][72];   // (q+u) [q][d]
    __shared__ unsigned short kh_[64][72], kl_[64][72];   // K     [k][d]
    __shared__ unsigned short rh_[128][72], rl_[128][72]; // R circ[slot][d]
    __shared__ unsigned short vth[64][72], vtl[64][72];   // V^T   [d][k]
    __shared__ unsigned short ph_[64][72], pl_[64][72];   // P     [q][k]
    __shared__ float s1f[64][68];                         // S1 scores
    __shared__ float s2f[64][132];                        // S2 window scores
    __shared__ float vc [128];                            // (v-u).R per slot
    __shared__ float uvd[64];
    __shared__ float alpha_s[64], l_s[64], m_s[64];

    const int qt  = blockIdx.x;
    const int hn  = blockIdx.y;
    const int b   = blockIdx.z;
    const int q0  = qt * 64;
    const int tid = threadIdx.x;

    const int wv = tid >> 6, ln = tid & 63;
    const int lr = ln & 15, lg = ln >> 4;
    const int qi = wv & 3,  g2 = wv >> 2;
    const int qr = tid >> 3, kc = tid & 7;

    // ---- prologue: stage (q+u) split; uvd; init m/l ----
#pragma unroll
    for (int it = 0; it < 2; ++it) {
        int idx = tid + it * 512;
        int dq = idx >> 4, d4 = idx & 15;
        const float* src = w + ((size_t)b * K_LEN + M_LEN + q0 + dq) * 1536 + hn * 64 + d4 * 4;
        float4 val = *(const float4*)src;
        float4 uu  = *(const float4*)(u + hn * 64 + d4 * 4);
        val.x += uu.x; val.y += uu.y; val.z += uu.z; val.w += uu.w;
        ushort4 h, l;
        split4(val, h, l);
        *(ushort4*)&quh[dq][d4 * 4] = h;
        *(ushort4*)&qul[dq][d4 * 4] = l;
    }
    if (tid < 64) {
        uvd[tid] = v[hn * 64 + tid] - u[hn * 64 + tid];
        m_s[tid] = -1e30f;
        l_s[tid] = 0.f;
    }
    __syncthreads();

    // hoist Q A-fragments (persistent across all tiles)
    bf16x8 qf_h[2], qf_l[2];
#pragma unroll
    for (int ks = 0; ks < 2; ++ks) {
        qf_h[ks] = *(const bf16x8*)&quh[qi * 16 + lr][ks * 32 + lg * 8];
        qf_l[ks] = *(const bf16x8*)&qul[qi * 16 + lr][ks * 32 + lg * 8];
    }

    // O accumulators: wave owns subtiles (qi, 2*g2+t), t=0,1
    f32x4 oc[2] = {{0.f,0.f,0.f,0.f},{0.f,0.f,0.f,0.f}};

    const int ntiles = qt + 17;

    // ---- prefetch tile 0 ----
    float4 kreg[2], vreg[2], rreg[4];
    {
        const int jb0 = 960 - q0;
#pragma unroll
        for (int it = 0; it < 2; ++it) {
            int idx = tid + it * 512;
            int kk = idx >> 4, d4 = idx & 15;
            const float* base = w + ((size_t)b * K_LEN + kk) * 1536 + hn * 64 + d4 * 4;
            kreg[it] = *(const float4*)(base + 512);
            vreg[it] = *(const float4*)(base + 1024);
        }
#pragma unroll
        for (int it = 0; it < 4; ++it) {
            int idx = tid + it * 512;
            int s = idx >> 4, d4 = idx & 15;
            int j = jb0 + s; j = j < 2047 ? j : 2047;
            rreg[it] = *(const float4*)(rproj + (size_t)j * 512 + hn * 64 + d4 * 4);
        }
    }

    for (int ti = 0; ti < ntiles; ++ti) {
        const int k0 = ti * 64;
        const int jb = k0 + 960 - q0;
        __syncthreads();   // previous tile fully consumed

        // ---- stage K split [k][d], V^T split [d][k], R split circ ----
#pragma unroll
        for (int it = 0; it < 2; ++it) {
            int idx = tid + it * 512;
            int kk = idx >> 4, d4 = idx & 15;
            ushort4 h, l;
            split4(kreg[it], h, l);
            *(ushort4*)&kh_[kk][d4 * 4] = h;
            *(ushort4*)&kl_[kk][d4 * 4] = l;
            ushort4 vh, vl;
            split4(vreg[it], vh, vl);
            vth[d4 * 4 + 0][kk] = vh.x; vth[d4 * 4 + 1][kk] = vh.y;
            vth[d4 * 4 + 2][kk] = vh.z; vth[d4 * 4 + 3][kk] = vh.w;
            vtl[d4 * 4 + 0][kk] = vl.x; vtl[d4 * 4 + 1][kk] = vl.y;
            vtl[d4 * 4 + 2][kk] = vl.z; vtl[d4 * 4 + 3][kk] = vl.w;
        }
        {
            int rn    = (ti == 0) ? 4 : 2;
            int rbase = (ti == 0) ? jb : jb + 64;
            for (int it = 0; it < rn; ++it) {
                int idx = tid + it * 512;
                int s = idx >> 4, d4 = idx & 15;
                int slot = (rbase + s) & 127;
                ushort4 h, l;
                split4(rreg[it], h, l);
                *(ushort4*)&rh_[slot][d4 * 4] = h;
                *(ushort4*)&rl_[slot][d4 * 4] = l;
            }
        }
        // ---- prefetch next tile ----
        if (ti + 1 < ntiles) {
            int k0n = k0 + 64;
#pragma unroll
            for (int it = 0; it < 2; ++it) {
                int idx = tid + it * 512;
                int kk = idx >> 4, d4 = idx & 15;
                const float* base = w + ((size_t)b * K_LEN + k0n + kk) * 1536 + hn * 64 + d4 * 4;
                kreg[it] = *(const float4*)(base + 512);
                vreg[it] = *(const float4*)(base + 1024);
            }
#pragma unroll
            for (int it = 0; it < 2; ++it) {
                int idx = tid + it * 512;
                int s = idx >> 4, d4 = idx & 15;
                int j = jb + 128 + s; j = j < 2047 ? j : 2047;
                rreg[it] = *(const float4*)(rproj + (size_t)j * 512 + hn * 64 + d4 * 4);
            }
        }
        __syncthreads();

        // ---- vc[t] = (v-u).R for new slots (waves 0-1; overlaps MFMA) ----
        {
            int nvc   = (ti == 0) ? 128 : 64;
            int vbase = (ti == 0) ? jb : jb + 64;
            if (tid < nvc) {
                int slot = (vbase + tid) & 127;
                float s = 0.f;
#pragma unroll 8
                for (int d = 0; d < 64; ++d) {
                    float rv = bf16_tof(rh_[slot][d]) + bf16_tof(rl_[slot][d]);
                    s = fmaf(uvd[d], rv, s);
                }
                vc[slot] = s;
            }
        }

        // ---- MFMA S1 (2 subtiles/wave), S2 (4 subtiles/wave) ----
        {
            f32x4 c1[2] = {{0.f,0.f,0.f,0.f},{0.f,0.f,0.f,0.f}};
            f32x4 c2[4] = {{0.f,0.f,0.f,0.f},{0.f,0.f,0.f,0.f},
                           {0.f,0.f,0.f,0.f},{0.f,0.f,0.f,0.f}};
#pragma unroll
            for (int ks = 0; ks < 2; ++ks) {
                const int dof = ks * 32 + lg * 8;
                bf16x8 ah = qf_h[ks], al = qf_l[ks];
#pragma unroll
                for (int t = 0; t < 2; ++t) {
                    int krow = (g2 * 2 + t) * 16 + lr;
                    bf16x8 bh = *(const bf16x8*)&kh_[krow][dof];
                    bf16x8 bl = *(const bf16x8*)&kl_[krow][dof];
                    c1[t] = __builtin_amdgcn_mfma_f32_16x16x32_bf16(ah, bh, c1[t], 0, 0, 0);
                    c1[t] = __builtin_amdgcn_mfma_f32_16x16x32_bf16(ah, bl, c1[t], 0, 0, 0);
                    c1[t] = __builtin_amdgcn_mfma_f32_16x16x32_bf16(al, bh, c1[t], 0, 0, 0);
                }
#pragma unroll
                for (int t = 0; t < 4; ++t) {
                    int slot = (jb + (g2 * 4 + t) * 16 + lr) & 127;
                    bf16x8 bh = *(const bf16x8*)&rh_[slot][dof];
                    bf16x8 bl = *(const bf16x8*)&rl_[slot][dof];
                    c2[t] = __builtin_amdgcn_mfma_f32_16x16x32_bf16(ah, bh, c2[t], 0, 0, 0);
                    c2[t] = __builtin_amdgcn_mfma_f32_16x16x32_bf16(ah, bl, c2[t], 0, 0, 0);
                    c2[t] = __builtin_amdgcn_mfma_f32_16x16x32_bf16(al, bh, c2[t], 0, 0, 0);
                }
            }
#pragma unroll
            for (int t = 0; t < 2; ++t)
#pragma unroll
                for (int r = 0; r < 4; ++r)
                    s1f[qi * 16 + lg * 4 + r][(g2 * 2 + t) * 16 + lr] = c1[t][r];
#pragma unroll
            for (int t = 0; t < 4; ++t)
#pragma unroll
                for (int r = 0; r < 4; ++r)
                    s2f[qi * 16 + lg * 4 + r][(g2 * 4 + t) * 16 + lr] = c2[t][r];
        }
        __syncthreads();

        // ---- online softmax (8 lanes per q-row); P -> split bf16 ----
        {
            float p[8];
            float mloc = -1e30f;
            const int q = q0 + qr;
            float s1v[8];
            *(float4*)&s1v[0] = *(const float4*)&s1f[qr][kc * 8];
            *(float4*)&s1v[4] = *(const float4*)&s1f[qr][kc * 8 + 4];
#pragma unroll
            for (int i = 0; i < 8; ++i) {
                int dk = kc * 8 + i;
                int t  = dk + 63 - qr;          // 0..126
                float x = (s1v[i] + s2f[qr][t] + vc[(jb + t) & 127]) * 0.125f;
                if (k0 + dk > q + M_LEN) x = -1e30f;
                p[i] = x;
                mloc = fmaxf(mloc, x);
            }
            mloc = fmaxf(mloc, __shfl_xor(mloc, 1));
            mloc = fmaxf(mloc, __shfl_xor(mloc, 2));
            mloc = fmaxf(mloc, __shfl_xor(mloc, 4));
            float mold = m_s[qr];
            float mnew = fmaxf(mold, mloc);
            float alpha = __expf(mold - mnew);
            float lsum = 0.f;
            unsigned short hb[8], lb[8];
#pragma unroll
            for (int i = 0; i < 8; ++i) {
                float pe = __expf(p[i] - mnew);
                lsum += pe;
                unsigned short h = bf16_rne(pe);
                hb[i] = h;
                lb[i] = bf16_rne(pe - bf16_tof(h));
            }
            lsum += __shfl_xor(lsum, 1);
            lsum += __shfl_xor(lsum, 2);
            lsum += __shfl_xor(lsum, 4);
            if (kc == 0) {
                m_s[qr]     = mnew;
                l_s[qr]     = l_s[qr] * alpha + lsum;
                alpha_s[qr] = alpha;
            }
            *(ushort4*)&ph_[qr][kc * 8]     = *(ushort4*)&hb[0];
            *(ushort4*)&ph_[qr][kc * 8 + 4] = *(ushort4*)&hb[4];
            *(ushort4*)&pl_[qr][kc * 8]     = *(ushort4*)&lb[0];
            *(ushort4*)&pl_[qr][kc * 8 + 4] = *(ushort4*)&lb[4];
        }
        __syncthreads();   // P, alpha ready; s1f/s2f free

        // ---- PV MFMA: O[qi][2*g2+t] += P . V ----
        {
            float ar[4];
#pragma unroll
            for (int r = 0; r < 4; ++r) ar[r] = alpha_s[qi * 16 + lg * 4 + r];
#pragma unroll
            for (int t = 0; t < 2; ++t)
#pragma unroll
                for (int r = 0; r < 4; ++r) oc[t][r] *= ar[r];
#pragma unroll
            for (int ks = 0; ks < 2; ++ks) {
                const int dof = ks * 32 + lg * 8;
                bf16x8 pa_h = *(const bf16x8*)&ph_[qi * 16 + lr][dof];
                bf16x8 pa_l = *(const bf16x8*)&pl_[qi * 16 + lr][dof];
#pragma unroll
                for (int t = 0; t < 2; ++t) {
                    int drow = (g2 * 2 + t) * 16 + lr;
                    bf16x8 bh = *(const bf16x8*)&vth[drow][dof];
                    bf16x8 bl = *(const bf16x8*)&vtl[drow][dof];
                    oc[t] = __builtin_amdgcn_mfma_f32_16x16x32_bf16(pa_h, bh, oc[t], 0, 0, 0);
                    oc[t] = __builtin_amdgcn_mfma_f32_16x16x32_bf16(pa_h, bl, oc[t], 0, 0, 0);
                    oc[t] = __builtin_amdgcn_mfma_f32_16x16x32_bf16(pa_l, bh, oc[t], 0, 0, 0);
                }
            }
        }
    }

    // ---- epilogue: normalize, store (b,q,n,d) ----
#pragma unroll
    for (int t = 0; t < 2; ++t) {
        int dcol = (g2 * 2 + t) * 16 + lr;
#pragma unroll
        for (int r = 0; r < 4; ++r) {
            int qq = qi * 16 + lg * 4 + r;
            float val = oc[t][r] / l_s[qq];
            out[(((size_t)b * Q_LEN + q0 + qq) * N_HEADS + hn) * D_K + dcol] = val;
        }
    }
}

// ---------------------------------------------------------------------------
extern "C" void kernel_launch(void* const* d_in, const int* in_sizes, int n_in,
                              void* d_out, int out_size, void* d_ws, size_t ws_size,
                              hipStream_t stream) {
    (void)in_sizes; (void)n_in; (void)out_size; (void)ws_size;

    const float* inputs = (const float*)d_in[0];
    const float* mem    = (const float*)d_in[1];
    const float* r      = (const float*)d_in[2];
    const float* Wqkv   = (const float*)d_in[3];
    const float* bqkv   = (const float*)d_in[4];
    const float* Wr     = (const float*)d_in[5];
    const float* br     = (const float*)d_in[6];
    const float* Wo     = (const float*)d_in[7];
    const float* bo     = (const float*)d_in[8];
    const float* u      = (const float*)d_in[9];
    const float* v      = (const float*)d_in[10];
    float* out = (float*)d_out;

    float* w     = (float*)d_ws;                   // 8192 x 1536 f32
    float* rproj = w + (size_t)8192 * 1536;        // 2048 x 512 f32
    float* attn  = rproj + (size_t)2048 * 512;     // 4096 x 512 f32
    unsigned short* wqkvh = (unsigned short*)(attn + (size_t)4096 * 512);
    unsigned short* wqkvl = wqkvh + (size_t)1536 * 512;
    unsigned short* wrh   = wqkvl + (size_t)1536 * 512;
    unsigned short* wrl   = wrh   + (size_t)512 * 512;
    unsigned short* woh   = wrl   + (size_t)512 * 512;
    unsigned short* wol   = woh   + (size_t)512 * 512;

    // 0) weight transpose + bf16 split (once per call)
    hipLaunchKernelGGL(prep_w, dim3(24, 8), dim3(256), 0, stream, Wqkv, wqkvh, wqkvl, 1536);
    hipLaunchKernelGGL(prep_w, dim3(8, 8),  dim3(256), 0, stream, Wr,   wrh,   wrl,   512);
    hipLaunchKernelGGL(prep_w, dim3(8, 8),  dim3(256), 0, stream, Wo,   woh,   wol,   512);

    // 1) QKV projection (concat): (8192 x 512) @ (512 x 1536)
    hipLaunchKernelGGL(gemm_mfma, dim3(64, 12), dim3(256), 0, stream,
                       mem, inputs, wqkvh, wqkvl, bqkv, w, 1536, 0);
    // 2) R projection: (2048 x 512) @ (512 x 512)
    hipLaunchKernelGGL(gemm_mfma, dim3(16, 4), dim3(256), 0, stream,
                       r, r, wrh, wrl, br, rproj, 512, 1);
    // 3) fused relative attention
    hipLaunchKernelGGL(attn_fused, dim3(16, 8, 4), dim3(512), 0, stream,
                       w, rproj, u, v, attn);
    // 4) output projection: (4096 x 512) @ (512 x 512)
    hipLaunchKernelGGL(gemm_mfma, dim3(32, 4), dim3(256), 0, stream,
                       attn, attn, woh, wol, bo, out, 512, 1);
}

// Round 6
// 469.059 us; speedup vs baseline: 2.3409x; 1.1253x over previous
//
#include <hip/hip_runtime.h>

#define D_MODEL 512
#define N_HEADS 8
#define D_K     64
#define BATCH   4
#define Q_LEN   1024
#define M_LEN   1024
#define K_LEN   2048

typedef short bf16x8 __attribute__((ext_vector_type(8)));
typedef float f32x4  __attribute__((ext_vector_type(4)));

__device__ __forceinline__ unsigned short bf16_rne(float x) {
    unsigned int u = __float_as_uint(x);
    return (unsigned short)((u + 0x7FFFu + ((u >> 16) & 1u)) >> 16);
}
__device__ __forceinline__ float bf16_tof(unsigned short h) {
    return __uint_as_float(((unsigned int)h) << 16);
}
__device__ __forceinline__ void split4(float4 x, ushort4& h, ushort4& l) {
    h.x = bf16_rne(x.x); h.y = bf16_rne(x.y);
    h.z = bf16_rne(x.z); h.w = bf16_rne(x.w);
    l.x = bf16_rne(x.x - bf16_tof(h.x));
    l.y = bf16_rne(x.y - bf16_tof(h.y));
    l.z = bf16_rne(x.z - bf16_tof(h.z));
    l.w = bf16_rne(x.w - bf16_tof(h.w));
}

// ---------------------------------------------------------------------------
// prep_w: W[512][N] (fp32) -> W^T hi/lo bf16 [N][512]. (unchanged)
// ---------------------------------------------------------------------------
__global__ __launch_bounds__(256)
void prep_w(const float* __restrict__ W, unsigned short* __restrict__ oh,
            unsigned short* __restrict__ ol, int N) {
    __shared__ float t[64][65];
    const int tid = threadIdx.x;
    const int nb = blockIdx.x * 64, kb = blockIdx.y * 64;
#pragma unroll
    for (int i = 0; i < 4; ++i) {
        int idx = tid + i * 256;
        int k = idx >> 4, n4 = idx & 15;
        float4 v = *(const float4*)(W + (size_t)(kb + k) * N + nb + n4 * 4);
        t[n4 * 4 + 0][k] = v.x;
        t[n4 * 4 + 1][k] = v.y;
        t[n4 * 4 + 2][k] = v.z;
        t[n4 * 4 + 3][k] = v.w;
    }
    __syncthreads();
    int n = tid >> 2, kq = (tid & 3) * 16;
    unsigned short hbuf[16], lbuf[16];
#pragma unroll
    for (int j = 0; j < 16; ++j) {
        float f = t[n][kq + j];
        unsigned short h = bf16_rne(f);
        hbuf[j] = h;
        lbuf[j] = bf16_rne(f - bf16_tof(h));
    }
    size_t base = (size_t)(nb + n) * 512 + kb + kq;
#pragma unroll
    for (int j = 0; j < 16; j += 4) {
        *(ushort4*)(oh + base + j) = *(ushort4*)&hbuf[j];
        *(ushort4*)(ol + base + j) = *(ushort4*)&lbuf[j];
    }
}

// ---------------------------------------------------------------------------
// Split-bf16 MFMA GEMM (unchanged from R5)
// ---------------------------------------------------------------------------
__global__ __launch_bounds__(256, 2)
void gemm_mfma(const float* __restrict__ a0, const float* __restrict__ a1,
               const unsigned short* __restrict__ bth,
               const unsigned short* __restrict__ btl,
               const float* __restrict__ bias, float* __restrict__ C,
               int N, int mode) {
    __shared__ unsigned short ah[128][40], al[128][40];
    __shared__ unsigned short bh[128][40], bl[128][40];
    const int tid  = threadIdx.x;
    const int row0 = blockIdx.x * 128, col0 = blockIdx.y * 128;
    const int ln = tid & 63, lr = ln & 15, lg = ln >> 4;
    const int wv = tid >> 6;
    const int ms = (wv & 1) * 64, ns = (wv >> 1) * 64;

    f32x4 c[4][4];
#pragma unroll
    for (int i = 0; i < 4; ++i)
#pragma unroll
        for (int j = 0; j < 4; ++j) c[i][j] = (f32x4){0.f, 0.f, 0.f, 0.f};

    for (int k0 = 0; k0 < 512; k0 += 32) {
#pragma unroll
        for (int i = 0; i < 4; ++i) {
            int idx = tid + i * 256;
            int m = idx >> 3, k4 = idx & 7;
            int row = row0 + m;
            const float* src;
            if (mode == 0) {
                int b = row >> 11, t = row & 2047;
                src = (t < M_LEN) ? (a0 + ((size_t)b * M_LEN + t) * 512)
                                  : (a1 + ((size_t)b * Q_LEN + (t - M_LEN)) * 512);
            } else {
                src = a0 + (size_t)row * 512;
            }
            float4 v = *(const float4*)(src + k0 + k4 * 4);
            ushort4 h, l;
            split4(v, h, l);
            *(ushort4*)&ah[m][k4 * 4] = h;
            *(ushort4*)&al[m][k4 * 4] = l;
        }
#pragma unroll
        for (int i = 0; i < 2; ++i) {
            int idx = tid + i * 256;
            int n = idx >> 2, kq = (idx & 3) * 8;
            size_t g = (size_t)(col0 + n) * 512 + k0 + kq;
            *(uint4*)&bh[n][kq] = *(const uint4*)(bth + g);
            *(uint4*)&bl[n][kq] = *(const uint4*)(btl + g);
        }
        __syncthreads();

        bf16x8 af_h[4], af_l[4], bf_h[4], bf_l[4];
#pragma unroll
        for (int i = 0; i < 4; ++i) {
            af_h[i] = *(const bf16x8*)&ah[ms + i * 16 + lr][lg * 8];
            af_l[i] = *(const bf16x8*)&al[ms + i * 16 + lr][lg * 8];
            bf_h[i] = *(const bf16x8*)&bh[ns + i * 16 + lr][lg * 8];
            bf_l[i] = *(const bf16x8*)&bl[ns + i * 16 + lr][lg * 8];
        }
#pragma unroll
        for (int i = 0; i < 4; ++i)
#pragma unroll
            for (int j = 0; j < 4; ++j) {
                c[i][j] = __builtin_amdgcn_mfma_f32_16x16x32_bf16(af_h[i], bf_h[j], c[i][j], 0, 0, 0);
                c[i][j] = __builtin_amdgcn_mfma_f32_16x16x32_bf16(af_h[i], bf_l[j], c[i][j], 0, 0, 0);
                c[i][j] = __builtin_amdgcn_mfma_f32_16x16x32_bf16(af_l[i], bf_h[j], c[i][j], 0, 0, 0);
            }
        __syncthreads();
    }

#pragma unroll
    for (int i = 0; i < 4; ++i) {
        int rbase = row0 + ms + i * 16 + lg * 4;
#pragma unroll
        for (int j = 0; j < 4; ++j) {
            int col = col0 + ns + j * 16 + lr;
            float bv = bias[col];
#pragma unroll
            for (int r = 0; r < 4; ++r)
                C[(size_t)(rbase + r) * N + col] = c[i][j][r] + bv;
        }
    }
}

// ---------------------------------------------------------------------------
// Fused relative attention — 2-stage software pipeline, 2 barriers per tile.
// Phase A: stage(ti) + prefetch(ti+1) + softmax(ti-1)
// Phase B: S1/S2 MFMA(ti) + PV MFMA(ti-1)
// S1 A-op = (q+u); S2 A-op = (q+v)  (both register-hoisted; no vc term).
// score[q,k] = (S1 + S2[t]) / 8,  t = k-k0 + 63 - (q-q0)
// ---------------------------------------------------------------------------
__global__ __launch_bounds__(512)
void attn_fused(const float* __restrict__ w, const float* __restrict__ rproj,
                const float* __restrict__ u, const float* __restrict__ v,
                float* __restrict__ out) {
    // qa_* stages Q in prologue, then becomes V^T buffer 1
    __shared__ unsigned short qa_h[64][72], qa_l[64][72];
    __shared__ unsigned short va_h[64][72], va_l[64][72];   // V^T buffer 0
    __shared__ unsigned short kh_[64][72], kl_[64][72];     // K [k][d]
    __shared__ unsigned short rh_[128][72], rl_[128][72];   // R circular [slot][d]
    __shared__ unsigned short ph_[64][72], pl_[64][72];     // P [q][k]
    __shared__ float s1f[64][68];                           // S1 [q][k]
    __shared__ float s2f[64][132];                          // S2 [q][t]
    __shared__ float alpha_s[64], l_s[64], m_s[64];

    const int qt  = blockIdx.x;
    const int hn  = blockIdx.y;
    const int b   = blockIdx.z;
    const int q0  = qt * 64;
    const int tid = threadIdx.x;

    const int wv = tid >> 6, ln = tid & 63;
    const int lr = ln & 15, lg = ln >> 4;
    const int qi = wv & 3,  g2 = wv >> 2;
    const int qr = tid >> 3, kc = tid & 7;

    // ---- prologue: hoist (q+u) and (q+v) A-fragments via qa_* staging ----
    bf16x8 qfu_h[2], qfu_l[2], qfv_h[2], qfv_l[2];
#pragma unroll
    for (int pass = 0; pass < 2; ++pass) {
        const float* bias_vec = pass == 0 ? u : v;
#pragma unroll
        for (int it = 0; it < 2; ++it) {
            int idx = tid + it * 512;
            int dq = idx >> 4, d4 = idx & 15;
            const float* src = w + ((size_t)b * K_LEN + M_LEN + q0 + dq) * 1536 + hn * 64 + d4 * 4;
            float4 val = *(const float4*)src;
            float4 uu  = *(const float4*)(bias_vec + hn * 64 + d4 * 4);
            val.x += uu.x; val.y += uu.y; val.z += uu.z; val.w += uu.w;
            ushort4 h, l;
            split4(val, h, l);
            *(ushort4*)&qa_h[dq][d4 * 4] = h;
            *(ushort4*)&qa_l[dq][d4 * 4] = l;
        }
        if (pass == 0 && tid < 64) { m_s[tid] = -1e30f; l_s[tid] = 0.f; }
        __syncthreads();
#pragma unroll
        for (int ks = 0; ks < 2; ++ks) {
            int dof = ks * 32 + lg * 8;
            if (pass == 0) {
                qfu_h[ks] = *(const bf16x8*)&qa_h[qi * 16 + lr][dof];
                qfu_l[ks] = *(const bf16x8*)&qa_l[qi * 16 + lr][dof];
            } else {
                qfv_h[ks] = *(const bf16x8*)&qa_h[qi * 16 + lr][dof];
                qfv_l[ks] = *(const bf16x8*)&qa_l[qi * 16 + lr][dof];
            }
        }
        __syncthreads();
    }

    // O accumulators: wave owns subtiles (qi, 2*g2+t)
    f32x4 oc[2] = {{0.f,0.f,0.f,0.f},{0.f,0.f,0.f,0.f}};

    const int ntiles = qt + 17;

    // ---- prefetch tile 0 into registers ----
    float4 kreg[2], vreg[2], rreg[4];
    {
        const int jb0 = 960 - q0;
#pragma unroll
        for (int it = 0; it < 2; ++it) {
            int idx = tid + it * 512;
            int kk = idx >> 4, d4 = idx & 15;
            const float* base = w + ((size_t)b * K_LEN + kk) * 1536 + hn * 64 + d4 * 4;
            kreg[it] = *(const float4*)(base + 512);
            vreg[it] = *(const float4*)(base + 1024);
        }
#pragma unroll
        for (int it = 0; it < 4; ++it) {
            int idx = tid + it * 512;
            int s = idx >> 4, d4 = idx & 15;
            int j = jb0 + s; j = j < 2047 ? j : 2047;
            rreg[it] = *(const float4*)(rproj + (size_t)j * 512 + hn * 64 + d4 * 4);
        }
    }

    for (int ti = 0; ti < ntiles; ++ti) {
        const int k0 = ti * 64;
        const int jb = k0 + 960 - q0;
        unsigned short (*vthp)[72] = (ti & 1) ? qa_h : va_h;
        unsigned short (*vtlp)[72] = (ti & 1) ? qa_l : va_l;

        __syncthreads();   // ===== sync1: phase B(ti-1) complete =====

        // ---- phase A (1): stage K, V^T(buf ti&1), R from prefetch regs ----
#pragma unroll
        for (int it = 0; it < 2; ++it) {
            int idx = tid + it * 512;
            int kk = idx >> 4, d4 = idx & 15;
            ushort4 h, l;
            split4(kreg[it], h, l);
            *(ushort4*)&kh_[kk][d4 * 4] = h;
            *(ushort4*)&kl_[kk][d4 * 4] = l;
            ushort4 vh, vl;
            split4(vreg[it], vh, vl);
            vthp[d4 * 4 + 0][kk] = vh.x; vthp[d4 * 4 + 1][kk] = vh.y;
            vthp[d4 * 4 + 2][kk] = vh.z; vthp[d4 * 4 + 3][kk] = vh.w;
            vtlp[d4 * 4 + 0][kk] = vl.x; vtlp[d4 * 4 + 1][kk] = vl.y;
            vtlp[d4 * 4 + 2][kk] = vl.z; vtlp[d4 * 4 + 3][kk] = vl.w;
        }
        {
            int rn    = (ti == 0) ? 4 : 2;
            int rbase = (ti == 0) ? jb : jb + 64;
            for (int it = 0; it < rn; ++it) {
                int idx = tid + it * 512;
                int s = idx >> 4, d4 = idx & 15;
                int slot = (rbase + s) & 127;
                ushort4 h, l;
                split4(rreg[it], h, l);
                *(ushort4*)&rh_[slot][d4 * 4] = h;
                *(ushort4*)&rl_[slot][d4 * 4] = l;
            }
        }
        // ---- phase A (2): issue global prefetch for ti+1 ----
        if (ti + 1 < ntiles) {
            int k0n = k0 + 64;
#pragma unroll
            for (int it = 0; it < 2; ++it) {
                int idx = tid + it * 512;
                int kk = idx >> 4, d4 = idx & 15;
                const float* base = w + ((size_t)b * K_LEN + k0n + kk) * 1536 + hn * 64 + d4 * 4;
                kreg[it] = *(const float4*)(base + 512);
                vreg[it] = *(const float4*)(base + 1024);
            }
#pragma unroll
            for (int it = 0; it < 2; ++it) {
                int idx = tid + it * 512;
                int s = idx >> 4, d4 = idx & 15;
                int j = jb + 128 + s; j = j < 2047 ? j : 2047;
                rreg[it] = *(const float4*)(rproj + (size_t)j * 512 + hn * 64 + d4 * 4);
            }
        }
        // ---- phase A (3): softmax(ti-1) ----
        if (ti > 0) {
            const int k0p = k0 - 64;
            float p[8];
            float mloc = -1e30f;
            const int q = q0 + qr;
            float s1v[8];
            *(float4*)&s1v[0] = *(const float4*)&s1f[qr][kc * 8];
            *(float4*)&s1v[4] = *(const float4*)&s1f[qr][kc * 8 + 4];
#pragma unroll
            for (int i = 0; i < 8; ++i) {
                int dk = kc * 8 + i;
                int t  = dk + 63 - qr;
                float x = (s1v[i] + s2f[qr][t]) * 0.125f;
                if (k0p + dk > q + M_LEN) x = -1e30f;
                p[i] = x;
                mloc = fmaxf(mloc, x);
            }
            mloc = fmaxf(mloc, __shfl_xor(mloc, 1));
            mloc = fmaxf(mloc, __shfl_xor(mloc, 2));
            mloc = fmaxf(mloc, __shfl_xor(mloc, 4));
            float mold = m_s[qr];
            float mnew = fmaxf(mold, mloc);
            float alpha = __expf(mold - mnew);
            float lsum = 0.f;
            unsigned short hb[8], lb[8];
#pragma unroll
            for (int i = 0; i < 8; ++i) {
                float pe = __expf(p[i] - mnew);
                lsum += pe;
                unsigned short h = bf16_rne(pe);
                hb[i] = h;
                lb[i] = bf16_rne(pe - bf16_tof(h));
            }
            lsum += __shfl_xor(lsum, 1);
            lsum += __shfl_xor(lsum, 2);
            lsum += __shfl_xor(lsum, 4);
            if (kc == 0) {
                m_s[qr]     = mnew;
                l_s[qr]     = l_s[qr] * alpha + lsum;
                alpha_s[qr] = alpha;
            }
            *(ushort4*)&ph_[qr][kc * 8]     = *(ushort4*)&hb[0];
            *(ushort4*)&ph_[qr][kc * 8 + 4] = *(ushort4*)&hb[4];
            *(ushort4*)&pl_[qr][kc * 8]     = *(ushort4*)&lb[0];
            *(ushort4*)&pl_[qr][kc * 8 + 4] = *(ushort4*)&lb[4];
        }

        __syncthreads();   // ===== sync2: staged tiles + P visible =====

        // ---- phase B (1): S1/S2 MFMA(ti) ----
        {
            f32x4 c1[2] = {{0.f,0.f,0.f,0.f},{0.f,0.f,0.f,0.f}};
            f32x4 c2[4] = {{0.f,0.f,0.f,0.f},{0.f,0.f,0.f,0.f},
                           {0.f,0.f,0.f,0.f},{0.f,0.f,0.f,0.f}};
#pragma unroll
            for (int ks = 0; ks < 2; ++ks) {
                const int dof = ks * 32 + lg * 8;
#pragma unroll
                for (int t = 0; t < 2; ++t) {
                    int krow = (g2 * 2 + t) * 16 + lr;
                    bf16x8 bh = *(const bf16x8*)&kh_[krow][dof];
                    bf16x8 bl = *(const bf16x8*)&kl_[krow][dof];
                    c1[t] = __builtin_amdgcn_mfma_f32_16x16x32_bf16(qfu_h[ks], bh, c1[t], 0, 0, 0);
                    c1[t] = __builtin_amdgcn_mfma_f32_16x16x32_bf16(qfu_h[ks], bl, c1[t], 0, 0, 0);
                    c1[t] = __builtin_amdgcn_mfma_f32_16x16x32_bf16(qfu_l[ks], bh, c1[t], 0, 0, 0);
                }
#pragma unroll
                for (int t = 0; t < 4; ++t) {
                    int slot = (jb + (g2 * 4 + t) * 16 + lr) & 127;
                    bf16x8 bh = *(const bf16x8*)&rh_[slot][dof];
                    bf16x8 bl = *(const bf16x8*)&rl_[slot][dof];
                    c2[t] = __builtin_amdgcn_mfma_f32_16x16x32_bf16(qfv_h[ks], bh, c2[t], 0, 0, 0);
                    c2[t] = __builtin_amdgcn_mfma_f32_16x16x32_bf16(qfv_h[ks], bl, c2[t], 0, 0, 0);
                    c2[t] = __builtin_amdgcn_mfma_f32_16x16x32_bf16(qfv_l[ks], bh, c2[t], 0, 0, 0);
                }
            }
#pragma unroll
            for (int t = 0; t < 2; ++t)
#pragma unroll
                for (int r = 0; r < 4; ++r)
                    s1f[qi * 16 + lg * 4 + r][(g2 * 2 + t) * 16 + lr] = c1[t][r];
#pragma unroll
            for (int t = 0; t < 4; ++t)
#pragma unroll
                for (int r = 0; r < 4; ++r)
                    s2f[qi * 16 + lg * 4 + r][(g2 * 4 + t) * 16 + lr] = c2[t][r];
        }
        // ---- phase B (2): PV MFMA(ti-1) ----
        if (ti > 0) {
            unsigned short (*pvh)[72] = ((ti - 1) & 1) ? qa_h : va_h;
            unsigned short (*pvl)[72] = ((ti - 1) & 1) ? qa_l : va_l;
            float ar[4];
#pragma unroll
            for (int r = 0; r < 4; ++r) ar[r] = alpha_s[qi * 16 + lg * 4 + r];
#pragma unroll
            for (int t = 0; t < 2; ++t)
#pragma unroll
                for (int r = 0; r < 4; ++r) oc[t][r] *= ar[r];
#pragma unroll
            for (int ks = 0; ks < 2; ++ks) {
                const int dof = ks * 32 + lg * 8;
                bf16x8 pa_h = *(const bf16x8*)&ph_[qi * 16 + lr][dof];
                bf16x8 pa_l = *(const bf16x8*)&pl_[qi * 16 + lr][dof];
#pragma unroll
                for (int t = 0; t < 2; ++t) {
                    int drow = (g2 * 2 + t) * 16 + lr;
                    bf16x8 bh = *(const bf16x8*)&pvh[drow][dof];
                    bf16x8 bl = *(const bf16x8*)&pvl[drow][dof];
                    oc[t] = __builtin_amdgcn_mfma_f32_16x16x32_bf16(pa_h, bh, oc[t], 0, 0, 0);
                    oc[t] = __builtin_amdgcn_mfma_f32_16x16x32_bf16(pa_h, bl, oc[t], 0, 0, 0);
                    oc[t] = __builtin_amdgcn_mfma_f32_16x16x32_bf16(pa_l, bh, oc[t], 0, 0, 0);
                }
            }
        }
    }

    // ---- epilogue: softmax + PV for last tile ----
    __syncthreads();
    {
        const int k0p = (ntiles - 1) * 64;
        float p[8];
        float mloc = -1e30f;
        const int q = q0 + qr;
        float s1v[8];
        *(float4*)&s1v[0] = *(const float4*)&s1f[qr][kc * 8];
        *(float4*)&s1v[4] = *(const float4*)&s1f[qr][kc * 8 + 4];
#pragma unroll
        for (int i = 0; i < 8; ++i) {
            int dk = kc * 8 + i;
            int t  = dk + 63 - qr;
            float x = (s1v[i] + s2f[qr][t]) * 0.125f;
            if (k0p + dk > q + M_LEN) x = -1e30f;
            p[i] = x;
            mloc = fmaxf(mloc, x);
        }
        mloc = fmaxf(mloc, __shfl_xor(mloc, 1));
        mloc = fmaxf(mloc, __shfl_xor(mloc, 2));
        mloc = fmaxf(mloc, __shfl_xor(mloc, 4));
        float mold = m_s[qr];
        float mnew = fmaxf(mold, mloc);
        float alpha = __expf(mold - mnew);
        float lsum = 0.f;
        unsigned short hb[8], lb[8];
#pragma unroll
        for (int i = 0; i < 8; ++i) {
            float pe = __expf(p[i] - mnew);
            lsum += pe;
            unsigned short h = bf16_rne(pe);
            hb[i] = h;
            lb[i] = bf16_rne(pe - bf16_tof(h));
        }
        lsum += __shfl_xor(lsum, 1);
        lsum += __shfl_xor(lsum, 2);
        lsum += __shfl_xor(lsum, 4);
        if (kc == 0) {
            l_s[qr]     = l_s[qr] * alpha + lsum;
            alpha_s[qr] = alpha;
        }
        *(ushort4*)&ph_[qr][kc * 8]     = *(ushort4*)&hb[0];
        *(ushort4*)&ph_[qr][kc * 8 + 4] = *(ushort4*)&hb[4];
        *(ushort4*)&pl_[qr][kc * 8]     = *(ushort4*)&lb[0];
        *(ushort4*)&pl_[qr][kc * 8 + 4] = *(ushort4*)&lb[4];
    }
    __syncthreads();
    {
        unsigned short (*pvh)[72] = ((ntiles - 1) & 1) ? qa_h : va_h;
        unsigned short (*pvl)[72] = ((ntiles - 1) & 1) ? qa_l : va_l;
        float ar[4];
#pragma unroll
        for (int r = 0; r < 4; ++r) ar[r] = alpha_s[qi * 16 + lg * 4 + r];
#pragma unroll
        for (int t = 0; t < 2; ++t)
#pragma unroll
            for (int r = 0; r < 4; ++r) oc[t][r] *= ar[r];
#pragma unroll
        for (int ks = 0; ks < 2; ++ks) {
            const int dof = ks * 32 + lg * 8;
            bf16x8 pa_h = *(const bf16x8*)&ph_[qi * 16 + lr][dof];
            bf16x8 pa_l = *(const bf16x8*)&pl_[qi * 16 + lr][dof];
#pragma unroll
            for (int t = 0; t < 2; ++t) {
                int drow = (g2 * 2 + t) * 16 + lr;
                bf16x8 bh = *(const bf16x8*)&pvh[drow][dof];
                bf16x8 bl = *(const bf16x8*)&pvl[drow][dof];
                oc[t] = __builtin_amdgcn_mfma_f32_16x16x32_bf16(pa_h, bh, oc[t], 0, 0, 0);
                oc[t] = __builtin_amdgcn_mfma_f32_16x16x32_bf16(pa_h, bl, oc[t], 0, 0, 0);
                oc[t] = __builtin_amdgcn_mfma_f32_16x16x32_bf16(pa_l, bh, oc[t], 0, 0, 0);
            }
        }
    }

    // ---- store (b,q,n,d) ----
#pragma unroll
    for (int t = 0; t < 2; ++t) {
        int dcol = (g2 * 2 + t) * 16 + lr;
#pragma unroll
        for (int r = 0; r < 4; ++r) {
            int qq = qi * 16 + lg * 4 + r;
            float val = oc[t][r] / l_s[qq];
            out[(((size_t)b * Q_LEN + q0 + qq) * N_HEADS + hn) * D_K + dcol] = val;
        }
    }
}

// ---------------------------------------------------------------------------
extern "C" void kernel_launch(void* const* d_in, const int* in_sizes, int n_in,
                              void* d_out, int out_size, void* d_ws, size_t ws_size,
                              hipStream_t stream) {
    (void)in_sizes; (void)n_in; (void)out_size; (void)ws_size;

    const float* inputs = (const float*)d_in[0];
    const float* mem    = (const float*)d_in[1];
    const float* r      = (const float*)d_in[2];
    const float* Wqkv   = (const float*)d_in[3];
    const float* bqkv   = (const float*)d_in[4];
    const float* Wr     = (const float*)d_in[5];
    const float* br     = (const float*)d_in[6];
    const float* Wo     = (const float*)d_in[7];
    const float* bo     = (const float*)d_in[8];
    const float* u      = (const float*)d_in[9];
    const float* v      = (const float*)d_in[10];
    float* out = (float*)d_out;

    float* w     = (float*)d_ws;                   // 8192 x 1536 f32
    float* rproj = w + (size_t)8192 * 1536;        // 2048 x 512 f32
    float* attn  = rproj + (size_t)2048 * 512;     // 4096 x 512 f32
    unsigned short* wqkvh = (unsigned short*)(attn + (size_t)4096 * 512);
    unsigned short* wqkvl = wqkvh + (size_t)1536 * 512;
    unsigned short* wrh   = wqkvl + (size_t)1536 * 512;
    unsigned short* wrl   = wrh   + (size_t)512 * 512;
    unsigned short* woh   = wrl   + (size_t)512 * 512;
    unsigned short* wol   = woh   + (size_t)512 * 512;

    hipLaunchKernelGGL(prep_w, dim3(24, 8), dim3(256), 0, stream, Wqkv, wqkvh, wqkvl, 1536);
    hipLaunchKernelGGL(prep_w, dim3(8, 8),  dim3(256), 0, stream, Wr,   wrh,   wrl,   512);
    hipLaunchKernelGGL(prep_w, dim3(8, 8),  dim3(256), 0, stream, Wo,   woh,   wol,   512);

    hipLaunchKernelGGL(gemm_mfma, dim3(64, 12), dim3(256), 0, stream,
                       mem, inputs, wqkvh, wqkvl, bqkv, w, 1536, 0);
    hipLaunchKernelGGL(gemm_mfma, dim3(16, 4), dim3(256), 0, stream,
                       r, r, wrh, wrl, br, rproj, 512, 1);
    hipLaunchKernelGGL(attn_fused, dim3(16, 8, 4), dim3(512), 0, stream,
                       w, rproj, u, v, attn);
    hipLaunchKernelGGL(gemm_mfma, dim3(32, 4), dim3(256), 0, stream,
                       attn, attn, woh, wol, bo, out, 512, 1);
}

// Round 8
// 453.931 us; speedup vs baseline: 2.4189x; 1.0333x over previous
//
#include <hip/hip_runtime.h>

#define D_MODEL 512
#define N_HEADS 8
#define D_K     64
#define BATCH   4
#define Q_LEN   1024
#define M_LEN   1024
#define K_LEN   2048

typedef short bf16x8 __attribute__((ext_vector_type(8)));
typedef float f32x4  __attribute__((ext_vector_type(4)));

__device__ __forceinline__ unsigned short bf16_rne(float x) {
    unsigned int u = __float_as_uint(x);
    return (unsigned short)((u + 0x7FFFu + ((u >> 16) & 1u)) >> 16);
}
__device__ __forceinline__ float bf16_tof(unsigned short h) {
    return __uint_as_float(((unsigned int)h) << 16);
}
__device__ __forceinline__ void split4(float4 x, ushort4& h, ushort4& l) {
    h.x = bf16_rne(x.x); h.y = bf16_rne(x.y);
    h.z = bf16_rne(x.z); h.w = bf16_rne(x.w);
    l.x = bf16_rne(x.x - bf16_tof(h.x));
    l.y = bf16_rne(x.y - bf16_tof(h.y));
    l.z = bf16_rne(x.z - bf16_tof(h.z));
    l.w = bf16_rne(x.w - bf16_tof(h.w));
}

// ---------------------------------------------------------------------------
// prep_w: W[512][N] (fp32) -> W^T hi/lo bf16 [N][512].
// ---------------------------------------------------------------------------
__global__ __launch_bounds__(256)
void prep_w(const float* __restrict__ W, unsigned short* __restrict__ oh,
            unsigned short* __restrict__ ol, int N) {
    __shared__ float t[64][65];
    const int tid = threadIdx.x;
    const int nb = blockIdx.x * 64, kb = blockIdx.y * 64;
#pragma unroll
    for (int i = 0; i < 4; ++i) {
        int idx = tid + i * 256;
        int k = idx >> 4, n4 = idx & 15;
        float4 v = *(const float4*)(W + (size_t)(kb + k) * N + nb + n4 * 4);
        t[n4 * 4 + 0][k] = v.x;
        t[n4 * 4 + 1][k] = v.y;
        t[n4 * 4 + 2][k] = v.z;
        t[n4 * 4 + 3][k] = v.w;
    }
    __syncthreads();
    int n = tid >> 2, kq = (tid & 3) * 16;
    unsigned short hbuf[16], lbuf[16];
#pragma unroll
    for (int j = 0; j < 16; ++j) {
        float f = t[n][kq + j];
        unsigned short h = bf16_rne(f);
        hbuf[j] = h;
        lbuf[j] = bf16_rne(f - bf16_tof(h));
    }
    size_t base = (size_t)(nb + n) * 512 + kb + kq;
#pragma unroll
    for (int j = 0; j < 16; j += 4) {
        *(ushort4*)(oh + base + j) = *(ushort4*)&hbuf[j];
        *(ushort4*)(ol + base + j) = *(ushort4*)&lbuf[j];
    }
}

// ---------------------------------------------------------------------------
// Split-bf16 MFMA GEMM
// ---------------------------------------------------------------------------
__global__ __launch_bounds__(256, 2)
void gemm_mfma(const float* __restrict__ a0, const float* __restrict__ a1,
               const unsigned short* __restrict__ bth,
               const unsigned short* __restrict__ btl,
               const float* __restrict__ bias, float* __restrict__ C,
               int N, int mode) {
    __shared__ unsigned short ah[128][40], al[128][40];
    __shared__ unsigned short bh[128][40], bl[128][40];
    const int tid  = threadIdx.x;
    const int row0 = blockIdx.x * 128, col0 = blockIdx.y * 128;
    const int ln = tid & 63, lr = ln & 15, lg = ln >> 4;
    const int wv = tid >> 6;
    const int ms = (wv & 1) * 64, ns = (wv >> 1) * 64;

    f32x4 c[4][4];
#pragma unroll
    for (int i = 0; i < 4; ++i)
#pragma unroll
        for (int j = 0; j < 4; ++j) c[i][j] = (f32x4){0.f, 0.f, 0.f, 0.f};

    for (int k0 = 0; k0 < 512; k0 += 32) {
#pragma unroll
        for (int i = 0; i < 4; ++i) {
            int idx = tid + i * 256;
            int m = idx >> 3, k4 = idx & 7;
            int row = row0 + m;
            const float* src;
            if (mode == 0) {
                int b = row >> 11, t = row & 2047;
                src = (t < M_LEN) ? (a0 + ((size_t)b * M_LEN + t) * 512)
                                  : (a1 + ((size_t)b * Q_LEN + (t - M_LEN)) * 512);
            } else {
                src = a0 + (size_t)row * 512;
            }
            float4 v = *(const float4*)(src + k0 + k4 * 4);
            ushort4 h, l;
            split4(v, h, l);
            *(ushort4*)&ah[m][k4 * 4] = h;
            *(ushort4*)&al[m][k4 * 4] = l;
        }
#pragma unroll
        for (int i = 0; i < 2; ++i) {
            int idx = tid + i * 256;
            int n = idx >> 2, kq = (idx & 3) * 8;
            size_t g = (size_t)(col0 + n) * 512 + k0 + kq;
            *(uint4*)&bh[n][kq] = *(const uint4*)(bth + g);
            *(uint4*)&bl[n][kq] = *(const uint4*)(btl + g);
        }
        __syncthreads();

        bf16x8 af_h[4], af_l[4], bf_h[4], bf_l[4];
#pragma unroll
        for (int i = 0; i < 4; ++i) {
            af_h[i] = *(const bf16x8*)&ah[ms + i * 16 + lr][lg * 8];
            af_l[i] = *(const bf16x8*)&al[ms + i * 16 + lr][lg * 8];
            bf_h[i] = *(const bf16x8*)&bh[ns + i * 16 + lr][lg * 8];
            bf_l[i] = *(const bf16x8*)&bl[ns + i * 16 + lr][lg * 8];
        }
#pragma unroll
        for (int i = 0; i < 4; ++i)
#pragma unroll
            for (int j = 0; j < 4; ++j) {
                c[i][j] = __builtin_amdgcn_mfma_f32_16x16x32_bf16(af_h[i], bf_h[j], c[i][j], 0, 0, 0);
                c[i][j] = __builtin_amdgcn_mfma_f32_16x16x32_bf16(af_h[i], bf_l[j], c[i][j], 0, 0, 0);
                c[i][j] = __builtin_amdgcn_mfma_f32_16x16x32_bf16(af_l[i], bf_h[j], c[i][j], 0, 0, 0);
            }
        __syncthreads();
    }

#pragma unroll
    for (int i = 0; i < 4; ++i) {
        int rbase = row0 + ms + i * 16 + lg * 4;
#pragma unroll
        for (int j = 0; j < 4; ++j) {
            int col = col0 + ns + j * 16 + lr;
            float bv = bias[col];
#pragma unroll
            for (int r = 0; r < 4; ++r)
                C[(size_t)(rbase + r) * N + col] = c[i][j][r] + bv;
        }
    }
}

// ---------------------------------------------------------------------------
// Fused relative attention — 1024 thr = 16 waves (4/SIMD), 2-stage pipeline.
// Phase A: stage(ti) + prefetch(ti+1) + softmax(ti-1)
// Phase B: S1/S2 MFMA(ti) + PV MFMA(ti-1)     [setprio around MFMA]
// Per wave: qi = wv&3 (q-group), g4 = wv>>2 (col-group of 16).
// score[q,k] = (S1 + S2[t]) / 8,  t = k-k0 + 63 - (q-q0)
// ---------------------------------------------------------------------------
__global__ __launch_bounds__(1024)
void attn_fused(const float* __restrict__ w, const float* __restrict__ rproj,
                const float* __restrict__ u, const float* __restrict__ v,
                float* __restrict__ out) {
    // qa_* stages Q in prologue, then becomes V^T buffer 1
    __shared__ unsigned short qa_h[64][72], qa_l[64][72];
    __shared__ unsigned short va_h[64][72], va_l[64][72];   // V^T buffer 0
    __shared__ unsigned short kh_[64][72], kl_[64][72];     // K [k][d]
    __shared__ unsigned short rh_[128][72], rl_[128][72];   // R circular [slot][d]
    __shared__ unsigned short ph_[64][72], pl_[64][72];     // P [q][k]
    __shared__ float s1f[64][68];                           // S1 [q][k]
    __shared__ float s2f[64][132];                          // S2 [q][t]
    __shared__ float alpha_s[64], l_s[64], m_s[64];

    const int qt  = blockIdx.x;
    const int hn  = blockIdx.y;
    const int b   = blockIdx.z;
    const int q0  = qt * 64;
    const int tid = threadIdx.x;

    const int wv = tid >> 6, ln = tid & 63;
    const int lr = ln & 15, lg = ln >> 4;
    const int qi = wv & 3,  g4 = wv >> 2;     // wave: q-group, col-group
    const int qr = tid >> 4, kc = tid & 15;   // softmax: row, 4-col chunk

    // ---- prologue: hoist (q+u) and (q+v) A-fragments via qa_* staging ----
    bf16x8 qfu_h[2], qfu_l[2], qfv_h[2], qfv_l[2];
#pragma unroll
    for (int pass = 0; pass < 2; ++pass) {
        const float* bias_vec = pass == 0 ? u : v;
        {
            int dq = tid >> 4, d4 = tid & 15;
            const float* src = w + ((size_t)b * K_LEN + M_LEN + q0 + dq) * 1536 + hn * 64 + d4 * 4;
            float4 val = *(const float4*)src;
            float4 uu  = *(const float4*)(bias_vec + hn * 64 + d4 * 4);
            val.x += uu.x; val.y += uu.y; val.z += uu.z; val.w += uu.w;
            ushort4 h, l;
            split4(val, h, l);
            *(ushort4*)&qa_h[dq][d4 * 4] = h;
            *(ushort4*)&qa_l[dq][d4 * 4] = l;
        }
        if (pass == 0 && tid < 64) { m_s[tid] = -1e30f; l_s[tid] = 0.f; }
        __syncthreads();
#pragma unroll
        for (int ks = 0; ks < 2; ++ks) {
            int dof = ks * 32 + lg * 8;
            if (pass == 0) {
                qfu_h[ks] = *(const bf16x8*)&qa_h[qi * 16 + lr][dof];
                qfu_l[ks] = *(const bf16x8*)&qa_l[qi * 16 + lr][dof];
            } else {
                qfv_h[ks] = *(const bf16x8*)&qa_h[qi * 16 + lr][dof];
                qfv_l[ks] = *(const bf16x8*)&qa_l[qi * 16 + lr][dof];
            }
        }
        __syncthreads();
    }

    // O accumulator: wave owns subtile (qi, g4)
    f32x4 oc = {0.f, 0.f, 0.f, 0.f};

    const int ntiles = qt + 17;

    // ---- prefetch tile 0 into registers ----
    float4 kreg, vreg, rreg[2];
    {
        const int jb0 = 960 - q0;
        int kk = tid >> 4, d4 = tid & 15;
        const float* base = w + ((size_t)b * K_LEN + kk) * 1536 + hn * 64 + d4 * 4;
        kreg = *(const float4*)(base + 512);
        vreg = *(const float4*)(base + 1024);
#pragma unroll
        for (int it = 0; it < 2; ++it) {
            int idx = tid + it * 1024;
            int s = idx >> 4, dd = idx & 15;
            int j = jb0 + s; j = j < 2047 ? j : 2047;
            rreg[it] = *(const float4*)(rproj + (size_t)j * 512 + hn * 64 + dd * 4);
        }
    }

    for (int ti = 0; ti < ntiles; ++ti) {
        const int k0 = ti * 64;
        const int jb = k0 + 960 - q0;
        unsigned short (*vthp)[72] = (ti & 1) ? qa_h : va_h;
        unsigned short (*vtlp)[72] = (ti & 1) ? qa_l : va_l;

        __syncthreads();   // ===== sync1: phase B(ti-1) complete =====

        // ---- phase A (1): stage K, V^T(buf ti&1), R from prefetch regs ----
        {
            int kk = tid >> 4, d4 = tid & 15;
            ushort4 h, l;
            split4(kreg, h, l);
            *(ushort4*)&kh_[kk][d4 * 4] = h;
            *(ushort4*)&kl_[kk][d4 * 4] = l;
            ushort4 vh, vl;
            split4(vreg, vh, vl);
            vthp[d4 * 4 + 0][kk] = vh.x; vthp[d4 * 4 + 1][kk] = vh.y;
            vthp[d4 * 4 + 2][kk] = vh.z; vthp[d4 * 4 + 3][kk] = vh.w;
            vtlp[d4 * 4 + 0][kk] = vl.x; vtlp[d4 * 4 + 1][kk] = vl.y;
            vtlp[d4 * 4 + 2][kk] = vl.z; vtlp[d4 * 4 + 3][kk] = vl.w;
        }
        {
            int rn    = (ti == 0) ? 2 : 1;
            int rbase = (ti == 0) ? jb : jb + 64;
            for (int it = 0; it < rn; ++it) {
                int idx = tid + it * 1024;
                int s = idx >> 4, d4 = idx & 15;
                int slot = (rbase + s) & 127;
                ushort4 h, l;
                split4(rreg[it], h, l);
                *(ushort4*)&rh_[slot][d4 * 4] = h;
                *(ushort4*)&rl_[slot][d4 * 4] = l;
            }
        }
        // ---- phase A (2): issue global prefetch for ti+1 ----
        if (ti + 1 < ntiles) {
            int k0n = k0 + 64;
            int kk = tid >> 4, d4 = tid & 15;
            const float* base = w + ((size_t)b * K_LEN + k0n + kk) * 1536 + hn * 64 + d4 * 4;
            kreg = *(const float4*)(base + 512);
            vreg = *(const float4*)(base + 1024);
            int s = tid >> 4;
            int j = jb + 128 + s; j = j < 2047 ? j : 2047;
            rreg[0] = *(const float4*)(rproj + (size_t)j * 512 + hn * 64 + d4 * 4);
        }
        // ---- phase A (3): softmax(ti-1), 16 lanes per q-row ----
        if (ti > 0) {
            const int k0p = k0 - 64;
            float p[4];
            float mloc = -1e30f;
            const int q = q0 + qr;
            float s1v[4];
            *(float4*)&s1v[0] = *(const float4*)&s1f[qr][kc * 4];
#pragma unroll
            for (int i = 0; i < 4; ++i) {
                int dk = kc * 4 + i;
                int t  = dk + 63 - qr;
                float x = (s1v[i] + s2f[qr][t]) * 0.125f;
                if (k0p + dk > q + M_LEN) x = -1e30f;
                p[i] = x;
                mloc = fmaxf(mloc, x);
            }
            mloc = fmaxf(mloc, __shfl_xor(mloc, 1));
            mloc = fmaxf(mloc, __shfl_xor(mloc, 2));
            mloc = fmaxf(mloc, __shfl_xor(mloc, 4));
            mloc = fmaxf(mloc, __shfl_xor(mloc, 8));
            float mold = m_s[qr];
            float mnew = fmaxf(mold, mloc);
            float alpha = __expf(mold - mnew);
            float lsum = 0.f;
            unsigned short hb[4], lb[4];
#pragma unroll
            for (int i = 0; i < 4; ++i) {
                float pe = __expf(p[i] - mnew);
                lsum += pe;
                unsigned short h = bf16_rne(pe);
                hb[i] = h;
                lb[i] = bf16_rne(pe - bf16_tof(h));
            }
            lsum += __shfl_xor(lsum, 1);
            lsum += __shfl_xor(lsum, 2);
            lsum += __shfl_xor(lsum, 4);
            lsum += __shfl_xor(lsum, 8);
            if (kc == 0) {
                m_s[qr]     = mnew;
                l_s[qr]     = l_s[qr] * alpha + lsum;
                alpha_s[qr] = alpha;
            }
            *(ushort4*)&ph_[qr][kc * 4] = *(ushort4*)&hb[0];
            *(ushort4*)&pl_[qr][kc * 4] = *(ushort4*)&lb[0];
        }

        __syncthreads();   // ===== sync2: staged tiles + P visible =====

        // ---- phase B (1): S1/S2 MFMA(ti) ----
        {
            f32x4 c1 = {0.f,0.f,0.f,0.f};
            f32x4 c2[2] = {{0.f,0.f,0.f,0.f},{0.f,0.f,0.f,0.f}};
            __builtin_amdgcn_s_setprio(1);
#pragma unroll
            for (int ks = 0; ks < 2; ++ks) {
                const int dof = ks * 32 + lg * 8;
                {
                    int krow = g4 * 16 + lr;
                    bf16x8 bh = *(const bf16x8*)&kh_[krow][dof];
                    bf16x8 bl = *(const bf16x8*)&kl_[krow][dof];
                    c1 = __builtin_amdgcn_mfma_f32_16x16x32_bf16(qfu_h[ks], bh, c1, 0, 0, 0);
                    c1 = __builtin_amdgcn_mfma_f32_16x16x32_bf16(qfu_h[ks], bl, c1, 0, 0, 0);
                    c1 = __builtin_amdgcn_mfma_f32_16x16x32_bf16(qfu_l[ks], bh, c1, 0, 0, 0);
                }
#pragma unroll
                for (int tt = 0; tt < 2; ++tt) {
                    int slot = (jb + (g4 * 2 + tt) * 16 + lr) & 127;
                    bf16x8 bh = *(const bf16x8*)&rh_[slot][dof];
                    bf16x8 bl = *(const bf16x8*)&rl_[slot][dof];
                    c2[tt] = __builtin_amdgcn_mfma_f32_16x16x32_bf16(qfv_h[ks], bh, c2[tt], 0, 0, 0);
                    c2[tt] = __builtin_amdgcn_mfma_f32_16x16x32_bf16(qfv_h[ks], bl, c2[tt], 0, 0, 0);
                    c2[tt] = __builtin_amdgcn_mfma_f32_16x16x32_bf16(qfv_l[ks], bh, c2[tt], 0, 0, 0);
                }
            }
            __builtin_amdgcn_s_setprio(0);
#pragma unroll
            for (int r = 0; r < 4; ++r)
                s1f[qi * 16 + lg * 4 + r][g4 * 16 + lr] = c1[r];
#pragma unroll
            for (int tt = 0; tt < 2; ++tt)
#pragma unroll
                for (int r = 0; r < 4; ++r)
                    s2f[qi * 16 + lg * 4 + r][(g4 * 2 + tt) * 16 + lr] = c2[tt][r];
        }
        // ---- phase B (2): PV MFMA(ti-1) ----
        if (ti > 0) {
            unsigned short (*pvh)[72] = ((ti - 1) & 1) ? qa_h : va_h;
            unsigned short (*pvl)[72] = ((ti - 1) & 1) ? qa_l : va_l;
            float ar[4];
#pragma unroll
            for (int r = 0; r < 4; ++r) ar[r] = alpha_s[qi * 16 + lg * 4 + r];
#pragma unroll
            for (int r = 0; r < 4; ++r) oc[r] *= ar[r];
            __builtin_amdgcn_s_setprio(1);
#pragma unroll
            for (int ks = 0; ks < 2; ++ks) {
                const int dof = ks * 32 + lg * 8;
                bf16x8 pa_h = *(const bf16x8*)&ph_[qi * 16 + lr][dof];
                bf16x8 pa_l = *(const bf16x8*)&pl_[qi * 16 + lr][dof];
                int drow = g4 * 16 + lr;
                bf16x8 bh = *(const bf16x8*)&pvh[drow][dof];
                bf16x8 bl = *(const bf16x8*)&pvl[drow][dof];
                oc = __builtin_amdgcn_mfma_f32_16x16x32_bf16(pa_h, bh, oc, 0, 0, 0);
                oc = __builtin_amdgcn_mfma_f32_16x16x32_bf16(pa_h, bl, oc, 0, 0, 0);
                oc = __builtin_amdgcn_mfma_f32_16x16x32_bf16(pa_l, bh, oc, 0, 0, 0);
            }
            __builtin_amdgcn_s_setprio(0);
        }
    }

    // ---- epilogue: softmax + PV for last tile ----
    __syncthreads();
    {
        const int k0p = (ntiles - 1) * 64;
        float p[4];
        float mloc = -1e30f;
        const int q = q0 + qr;
        float s1v[4];
        *(float4*)&s1v[0] = *(const float4*)&s1f[qr][kc * 4];
#pragma unroll
        for (int i = 0; i < 4; ++i) {
            int dk = kc * 4 + i;
            int t  = dk + 63 - qr;
            float x = (s1v[i] + s2f[qr][t]) * 0.125f;
            if (k0p + dk > q + M_LEN) x = -1e30f;
            p[i] = x;
            mloc = fmaxf(mloc, x);
        }
        mloc = fmaxf(mloc, __shfl_xor(mloc, 1));
        mloc = fmaxf(mloc, __shfl_xor(mloc, 2));
        mloc = fmaxf(mloc, __shfl_xor(mloc, 4));
        mloc = fmaxf(mloc, __shfl_xor(mloc, 8));
        float mold = m_s[qr];
        float mnew = fmaxf(mold, mloc);
        float alpha = __expf(mold - mnew);
        float lsum = 0.f;
        unsigned short hb[4], lb[4];
#pragma unroll
        for (int i = 0; i < 4; ++i) {
            float pe = __expf(p[i] - mnew);
            lsum += pe;
            unsigned short h = bf16_rne(pe);
            hb[i] = h;
            lb[i] = bf16_rne(pe - bf16_tof(h));
        }
        lsum += __shfl_xor(lsum, 1);
        lsum += __shfl_xor(lsum, 2);
        lsum += __shfl_xor(lsum, 4);
        lsum += __shfl_xor(lsum, 8);
        if (kc == 0) {
            l_s[qr]     = l_s[qr] * alpha + lsum;
            alpha_s[qr] = alpha;
        }
        *(ushort4*)&ph_[qr][kc * 4] = *(ushort4*)&hb[0];
        *(ushort4*)&pl_[qr][kc * 4] = *(ushort4*)&lb[0];
    }
    __syncthreads();
    {
        unsigned short (*pvh)[72] = ((ntiles - 1) & 1) ? qa_h : va_h;
        unsigned short (*pvl)[72] = ((ntiles - 1) & 1) ? qa_l : va_l;
        float ar[4];
#pragma unroll
        for (int r = 0; r < 4; ++r) ar[r] = alpha_s[qi * 16 + lg * 4 + r];
#pragma unroll
        for (int r = 0; r < 4; ++r) oc[r] *= ar[r];
#pragma unroll
        for (int ks = 0; ks < 2; ++ks) {
            const int dof = ks * 32 + lg * 8;
            bf16x8 pa_h = *(const bf16x8*)&ph_[qi * 16 + lr][dof];
            bf16x8 pa_l = *(const bf16x8*)&pl_[qi * 16 + lr][dof];
            int drow = g4 * 16 + lr;
            bf16x8 bh = *(const bf16x8*)&pvh[drow][dof];
            bf16x8 bl = *(const bf16x8*)&pvl[drow][dof];
            oc = __builtin_amdgcn_mfma_f32_16x16x32_bf16(pa_h, bh, oc, 0, 0, 0);
            oc = __builtin_amdgcn_mfma_f32_16x16x32_bf16(pa_h, bl, oc, 0, 0, 0);
            oc = __builtin_amdgcn_mfma_f32_16x16x32_bf16(pa_l, bh, oc, 0, 0, 0);
        }
    }

    // ---- store (b,q,n,d) ----
    {
        int dcol = g4 * 16 + lr;
#pragma unroll
        for (int r = 0; r < 4; ++r) {
            int qq = qi * 16 + lg * 4 + r;
            float val = oc[r] / l_s[qq];
            out[(((size_t)b * Q_LEN + q0 + qq) * N_HEADS + hn) * D_K + dcol] = val;
        }
    }
}

// ---------------------------------------------------------------------------
extern "C" void kernel_launch(void* const* d_in, const int* in_sizes, int n_in,
                              void* d_out, int out_size, void* d_ws, size_t ws_size,
                              hipStream_t stream) {
    (void)in_sizes; (void)n_in; (void)out_size; (void)ws_size;

    const float* inputs = (const float*)d_in[0];
    const float* mem    = (const float*)d_in[1];
    const float* r      = (const float*)d_in[2];
    const float* Wqkv   = (const float*)d_in[3];
    const float* bqkv   = (const float*)d_in[4];
    const float* Wr     = (const float*)d_in[5];
    const float* br     = (const float*)d_in[6];
    const float* Wo     = (const float*)d_in[7];
    const float* bo     = (const float*)d_in[8];
    const float* u      = (const float*)d_in[9];
    const float* v      = (const float*)d_in[10];
    float* out = (float*)d_out;

    float* w     = (float*)d_ws;                   // 8192 x 1536 f32
    float* rproj = w + (size_t)8192 * 1536;        // 2048 x 512 f32
    float* attn  = rproj + (size_t)2048 * 512;     // 4096 x 512 f32
    unsigned short* wqkvh = (unsigned short*)(attn + (size_t)4096 * 512);
    unsigned short* wqkvl = wqkvh + (size_t)1536 * 512;
    unsigned short* wrh   = wqkvl + (size_t)1536 * 512;
    unsigned short* wrl   = wrh   + (size_t)512 * 512;
    unsigned short* woh   = wrl   + (size_t)512 * 512;
    unsigned short* wol   = woh   + (size_t)512 * 512;

    hipLaunchKernelGGL(prep_w, dim3(24, 8), dim3(256), 0, stream, Wqkv, wqkvh, wqkvl, 1536);
    hipLaunchKernelGGL(prep_w, dim3(8, 8),  dim3(256), 0, stream, Wr,   wrh,   wrl,   512);
    hipLaunchKernelGGL(prep_w, dim3(8, 8),  dim3(256), 0, stream, Wo,   woh,   wol,   512);

    hipLaunchKernelGGL(gemm_mfma, dim3(64, 12), dim3(256), 0, stream,
                       mem, inputs, wqkvh, wqkvl, bqkv, w, 1536, 0);
    hipLaunchKernelGGL(gemm_mfma, dim3(16, 4), dim3(256), 0, stream,
                       r, r, wrh, wrl, br, rproj, 512, 1);
    hipLaunchKernelGGL(attn_fused, dim3(16, 8, 4), dim3(1024), 0, stream,
                       w, rproj, u, v, attn);
    hipLaunchKernelGGL(gemm_mfma, dim3(32, 4), dim3(256), 0, stream,
                       attn, attn, woh, wol, bo, out, 512, 1);
}

// Round 9
// 424.571 us; speedup vs baseline: 2.5861x; 1.0692x over previous
//
#include <hip/hip_runtime.h>

#define D_MODEL 512
#define N_HEADS 8
#define D_K     64
#define BATCH   4
#define Q_LEN   1024
#define M_LEN   1024
#define K_LEN   2048

typedef short bf16x8 __attribute__((ext_vector_type(8)));
typedef float f32x4  __attribute__((ext_vector_type(4)));

__device__ __forceinline__ unsigned short bf16_rne(float x) {
    unsigned int u = __float_as_uint(x);
    return (unsigned short)((u + 0x7FFFu + ((u >> 16) & 1u)) >> 16);
}
__device__ __forceinline__ float bf16_tof(unsigned short h) {
    return __uint_as_float(((unsigned int)h) << 16);
}
__device__ __forceinline__ void split4(float4 x, ushort4& h, ushort4& l) {
    h.x = bf16_rne(x.x); h.y = bf16_rne(x.y);
    h.z = bf16_rne(x.z); h.w = bf16_rne(x.w);
    l.x = bf16_rne(x.x - bf16_tof(h.x));
    l.y = bf16_rne(x.y - bf16_tof(h.y));
    l.z = bf16_rne(x.z - bf16_tof(h.z));
    l.w = bf16_rne(x.w - bf16_tof(h.w));
}

// ---------------------------------------------------------------------------
// prep_w: W[512][N] (fp32) -> W^T hi/lo bf16 [N][512].
// ---------------------------------------------------------------------------
__global__ __launch_bounds__(256)
void prep_w(const float* __restrict__ W, unsigned short* __restrict__ oh,
            unsigned short* __restrict__ ol, int N) {
    __shared__ float t[64][65];
    const int tid = threadIdx.x;
    const int nb = blockIdx.x * 64, kb = blockIdx.y * 64;
#pragma unroll
    for (int i = 0; i < 4; ++i) {
        int idx = tid + i * 256;
        int k = idx >> 4, n4 = idx & 15;
        float4 v = *(const float4*)(W + (size_t)(kb + k) * N + nb + n4 * 4);
        t[n4 * 4 + 0][k] = v.x;
        t[n4 * 4 + 1][k] = v.y;
        t[n4 * 4 + 2][k] = v.z;
        t[n4 * 4 + 3][k] = v.w;
    }
    __syncthreads();
    int n = tid >> 2, kq = (tid & 3) * 16;
    unsigned short hbuf[16], lbuf[16];
#pragma unroll
    for (int j = 0; j < 16; ++j) {
        float f = t[n][kq + j];
        unsigned short h = bf16_rne(f);
        hbuf[j] = h;
        lbuf[j] = bf16_rne(f - bf16_tof(h));
    }
    size_t base = (size_t)(nb + n) * 512 + kb + kq;
#pragma unroll
    for (int j = 0; j < 16; j += 4) {
        *(ushort4*)(oh + base + j) = *(ushort4*)&hbuf[j];
        *(ushort4*)(ol + base + j) = *(ushort4*)&lbuf[j];
    }
}

// ---------------------------------------------------------------------------
// Split-bf16 MFMA GEMM.  Output: either fp32 C, or split-bf16 (Ch/Cl).
// ---------------------------------------------------------------------------
__global__ __launch_bounds__(256, 2)
void gemm_mfma(const float* __restrict__ a0, const float* __restrict__ a1,
               const unsigned short* __restrict__ bth,
               const unsigned short* __restrict__ btl,
               const float* __restrict__ bias, float* __restrict__ C,
               unsigned short* __restrict__ Ch, unsigned short* __restrict__ Cl,
               int N, int mode) {
    __shared__ unsigned short ah[128][40], al[128][40];
    __shared__ unsigned short bh[128][40], bl[128][40];
    const int tid  = threadIdx.x;
    const int row0 = blockIdx.x * 128, col0 = blockIdx.y * 128;
    const int ln = tid & 63, lr = ln & 15, lg = ln >> 4;
    const int wv = tid >> 6;
    const int ms = (wv & 1) * 64, ns = (wv >> 1) * 64;

    f32x4 c[4][4];
#pragma unroll
    for (int i = 0; i < 4; ++i)
#pragma unroll
        for (int j = 0; j < 4; ++j) c[i][j] = (f32x4){0.f, 0.f, 0.f, 0.f};

    for (int k0 = 0; k0 < 512; k0 += 32) {
#pragma unroll
        for (int i = 0; i < 4; ++i) {
            int idx = tid + i * 256;
            int m = idx >> 3, k4 = idx & 7;
            int row = row0 + m;
            const float* src;
            if (mode == 0) {
                int b = row >> 11, t = row & 2047;
                src = (t < M_LEN) ? (a0 + ((size_t)b * M_LEN + t) * 512)
                                  : (a1 + ((size_t)b * Q_LEN + (t - M_LEN)) * 512);
            } else {
                src = a0 + (size_t)row * 512;
            }
            float4 v = *(const float4*)(src + k0 + k4 * 4);
            ushort4 h, l;
            split4(v, h, l);
            *(ushort4*)&ah[m][k4 * 4] = h;
            *(ushort4*)&al[m][k4 * 4] = l;
        }
#pragma unroll
        for (int i = 0; i < 2; ++i) {
            int idx = tid + i * 256;
            int n = idx >> 2, kq = (idx & 3) * 8;
            size_t g = (size_t)(col0 + n) * 512 + k0 + kq;
            *(uint4*)&bh[n][kq] = *(const uint4*)(bth + g);
            *(uint4*)&bl[n][kq] = *(const uint4*)(btl + g);
        }
        __syncthreads();

        bf16x8 af_h[4], af_l[4], bf_h[4], bf_l[4];
#pragma unroll
        for (int i = 0; i < 4; ++i) {
            af_h[i] = *(const bf16x8*)&ah[ms + i * 16 + lr][lg * 8];
            af_l[i] = *(const bf16x8*)&al[ms + i * 16 + lr][lg * 8];
            bf_h[i] = *(const bf16x8*)&bh[ns + i * 16 + lr][lg * 8];
            bf_l[i] = *(const bf16x8*)&bl[ns + i * 16 + lr][lg * 8];
        }
#pragma unroll
        for (int i = 0; i < 4; ++i)
#pragma unroll
            for (int j = 0; j < 4; ++j) {
                c[i][j] = __builtin_amdgcn_mfma_f32_16x16x32_bf16(af_h[i], bf_h[j], c[i][j], 0, 0, 0);
                c[i][j] = __builtin_amdgcn_mfma_f32_16x16x32_bf16(af_h[i], bf_l[j], c[i][j], 0, 0, 0);
                c[i][j] = __builtin_amdgcn_mfma_f32_16x16x32_bf16(af_l[i], bf_h[j], c[i][j], 0, 0, 0);
            }
        __syncthreads();
    }

#pragma unroll
    for (int i = 0; i < 4; ++i) {
        int rbase = row0 + ms + i * 16 + lg * 4;
#pragma unroll
        for (int j = 0; j < 4; ++j) {
            int col = col0 + ns + j * 16 + lr;
            float bv = bias[col];
            if (Ch) {
#pragma unroll
                for (int r = 0; r < 4; ++r) {
                    float val = c[i][j][r] + bv;
                    unsigned short h = bf16_rne(val);
                    unsigned short l = bf16_rne(val - bf16_tof(h));
                    size_t off = (size_t)(rbase + r) * N + col;
                    Ch[off] = h;
                    Cl[off] = l;
                }
            } else {
#pragma unroll
                for (int r = 0; r < 4; ++r)
                    C[(size_t)(rbase + r) * N + col] = c[i][j][r] + bv;
            }
        }
    }
}

// ---------------------------------------------------------------------------
// Fused relative attention — 1024 thr = 16 waves (4/SIMD), 2-stage pipeline,
// pre-split bf16 inputs (wsh/wsl = QKV split, rph/rpl = R-proj split).
// Balanced qt remap: block idx & idx+256 get complementary qt.
// Phase A: stage(ti) + prefetch(ti+1) + softmax(ti-1)
// Phase B: S1/S2 MFMA(ti) + PV MFMA(ti-1)     [setprio around MFMA]
// score[q,k] = (S1 + S2[t]) / 8,  t = k-k0 + 63 - (q-q0)
// ---------------------------------------------------------------------------
__global__ __launch_bounds__(1024)
void attn_fused(const unsigned short* __restrict__ wsh,
                const unsigned short* __restrict__ wsl,
                const unsigned short* __restrict__ rph,
                const unsigned short* __restrict__ rpl,
                const float* __restrict__ u, const float* __restrict__ v,
                float* __restrict__ out) {
    // qa_* stages Q in prologue, then becomes V^T buffer 1
    __shared__ unsigned short qa_h[64][72], qa_l[64][72];
    __shared__ unsigned short va_h[64][72], va_l[64][72];   // V^T buffer 0
    __shared__ unsigned short kh_[64][72], kl_[64][72];     // K [k][d]
    __shared__ unsigned short rh_[128][72], rl_[128][72];   // R circular [slot][d]
    __shared__ unsigned short ph_[64][72], pl_[64][72];     // P [q][k]
    __shared__ float s1f[64][68];                           // S1 [q][k]
    __shared__ float s2f[64][132];                          // S2 [q][t]
    __shared__ float alpha_s[64], l_s[64], m_s[64];

    // balanced decomposition: idx and idx+256 have complementary qt
    const int idx  = blockIdx.x;
    const int pass = idx >> 8;
    const int slot = idx & 255;
    const int qt   = pass ? 15 - (slot & 15) : (slot & 15);
    const int hn   = (slot >> 4) & 7;
    const int b    = (slot >> 7) + pass * 2;

    const int q0  = qt * 64;
    const int tid = threadIdx.x;

    const int wv = tid >> 6, ln = tid & 63;
    const int lr = ln & 15, lg = ln >> 4;
    const int qi = wv & 3,  g4 = wv >> 2;     // wave: q-group, col-group
    const int qr = tid >> 4, kc = tid & 15;   // softmax: row, 4-col chunk

    // ---- prologue: hoist (q+u) and (q+v) A-fragments via qa_* staging ----
    bf16x8 qfu_h[2], qfu_l[2], qfv_h[2], qfv_l[2];
#pragma unroll
    for (int pp = 0; pp < 2; ++pp) {
        const float* bias_vec = pp == 0 ? u : v;
        {
            int dq = tid >> 4, d4 = tid & 15;
            size_t off = ((size_t)b * K_LEN + M_LEN + q0 + dq) * 1536 + hn * 64 + d4 * 4;
            ushort4 qh = *(const ushort4*)(wsh + off);
            ushort4 ql = *(const ushort4*)(wsl + off);
            float4 uu  = *(const float4*)(bias_vec + hn * 64 + d4 * 4);
            float4 val;
            val.x = bf16_tof(qh.x) + bf16_tof(ql.x) + uu.x;
            val.y = bf16_tof(qh.y) + bf16_tof(ql.y) + uu.y;
            val.z = bf16_tof(qh.z) + bf16_tof(ql.z) + uu.z;
            val.w = bf16_tof(qh.w) + bf16_tof(ql.w) + uu.w;
            ushort4 h, l;
            split4(val, h, l);
            *(ushort4*)&qa_h[dq][d4 * 4] = h;
            *(ushort4*)&qa_l[dq][d4 * 4] = l;
        }
        if (pp == 0 && tid < 64) { m_s[tid] = -1e30f; l_s[tid] = 0.f; }
        __syncthreads();
#pragma unroll
        for (int ks = 0; ks < 2; ++ks) {
            int dof = ks * 32 + lg * 8;
            if (pp == 0) {
                qfu_h[ks] = *(const bf16x8*)&qa_h[qi * 16 + lr][dof];
                qfu_l[ks] = *(const bf16x8*)&qa_l[qi * 16 + lr][dof];
            } else {
                qfv_h[ks] = *(const bf16x8*)&qa_h[qi * 16 + lr][dof];
                qfv_l[ks] = *(const bf16x8*)&qa_l[qi * 16 + lr][dof];
            }
        }
        __syncthreads();
    }

    // O accumulator: wave owns subtile (qi, g4)
    f32x4 oc = {0.f, 0.f, 0.f, 0.f};

    const int ntiles = qt + 17;

    // ---- prefetch tile 0 into registers (pre-split ushort4 pairs) ----
    ushort4 krh, krl, vrh[2], vrl[2], rrh[2], rrl[2];
    {
        const int jb0 = 960 - q0;
        {
            int kk = tid >> 4, d4 = tid & 15;
            size_t off = ((size_t)b * K_LEN + kk) * 1536 + 512 + hn * 64 + d4 * 4;
            krh = *(const ushort4*)(wsh + off);
            krl = *(const ushort4*)(wsl + off);
        }
        if (tid < 512) {
            int r2 = tid >> 4, d4 = tid & 15;
            size_t off = ((size_t)b * K_LEN + 2 * r2) * 1536 + 1024 + hn * 64 + d4 * 4;
            vrh[0] = *(const ushort4*)(wsh + off);
            vrl[0] = *(const ushort4*)(wsl + off);
            vrh[1] = *(const ushort4*)(wsh + off + 1536);
            vrl[1] = *(const ushort4*)(wsl + off + 1536);
        }
#pragma unroll
        for (int it = 0; it < 2; ++it) {
            int ii = tid + it * 1024;
            int s = ii >> 4, d4 = ii & 15;
            int j = jb0 + s; j = j < 2047 ? j : 2047;
            size_t off = (size_t)j * 512 + hn * 64 + d4 * 4;
            rrh[it] = *(const ushort4*)(rph + off);
            rrl[it] = *(const ushort4*)(rpl + off);
        }
    }

    for (int ti = 0; ti < ntiles; ++ti) {
        const int k0 = ti * 64;
        const int jb = k0 + 960 - q0;
        unsigned short (*vthp)[72] = (ti & 1) ? qa_h : va_h;
        unsigned short (*vtlp)[72] = (ti & 1) ? qa_l : va_l;

        __syncthreads();   // ===== sync1: phase B(ti-1) complete =====

        // ---- phase A (1): stage K, V^T(buf ti&1), R (pure copies) ----
        {
            int kk = tid >> 4, d4 = tid & 15;
            *(ushort4*)&kh_[kk][d4 * 4] = krh;
            *(ushort4*)&kl_[kk][d4 * 4] = krl;
        }
        if (tid < 512) {
            int r2 = tid >> 4, d4 = tid & 15;
#pragma unroll
            for (int j = 0; j < 4; ++j) {
                ushort2 hh; hh.x = ((unsigned short*)&vrh[0])[j]; hh.y = ((unsigned short*)&vrh[1])[j];
                ushort2 ll; ll.x = ((unsigned short*)&vrl[0])[j]; ll.y = ((unsigned short*)&vrl[1])[j];
                *(ushort2*)&vthp[d4 * 4 + j][2 * r2] = hh;
                *(ushort2*)&vtlp[d4 * 4 + j][2 * r2] = ll;
            }
        }
        {
            int rn    = (ti == 0) ? 2 : 1;
            int rbase = (ti == 0) ? jb : jb + 64;
            for (int it = 0; it < rn; ++it) {
                int ii = tid + it * 1024;
                int s = ii >> 4, d4 = ii & 15;
                int sl = (rbase + s) & 127;
                *(ushort4*)&rh_[sl][d4 * 4] = rrh[it];
                *(ushort4*)&rl_[sl][d4 * 4] = rrl[it];
            }
        }
        // ---- phase A (2): issue global prefetch for ti+1 ----
        if (ti + 1 < ntiles) {
            int k0n = k0 + 64;
            {
                int kk = tid >> 4, d4 = tid & 15;
                size_t off = ((size_t)b * K_LEN + k0n + kk) * 1536 + 512 + hn * 64 + d4 * 4;
                krh = *(const ushort4*)(wsh + off);
                krl = *(const ushort4*)(wsl + off);
            }
            if (tid < 512) {
                int r2 = tid >> 4, d4 = tid & 15;
                size_t off = ((size_t)b * K_LEN + k0n + 2 * r2) * 1536 + 1024 + hn * 64 + d4 * 4;
                vrh[0] = *(const ushort4*)(wsh + off);
                vrl[0] = *(const ushort4*)(wsl + off);
                vrh[1] = *(const ushort4*)(wsh + off + 1536);
                vrl[1] = *(const ushort4*)(wsl + off + 1536);
            }
            {
                int s = tid >> 4, d4 = tid & 15;
                int j = jb + 128 + s; j = j < 2047 ? j : 2047;
                size_t off = (size_t)j * 512 + hn * 64 + d4 * 4;
                rrh[0] = *(const ushort4*)(rph + off);
                rrl[0] = *(const ushort4*)(rpl + off);
            }
        }
        // ---- phase A (3): softmax(ti-1), 16 lanes per q-row ----
        if (ti > 0) {
            const int k0p = k0 - 64;
            float p[4];
            float mloc = -1e30f;
            const int q = q0 + qr;
            float s1v[4];
            *(float4*)&s1v[0] = *(const float4*)&s1f[qr][kc * 4];
#pragma unroll
            for (int i = 0; i < 4; ++i) {
                int dk = kc * 4 + i;
                int t  = dk + 63 - qr;
                float x = (s1v[i] + s2f[qr][t]) * 0.125f;
                if (k0p + dk > q + M_LEN) x = -1e30f;
                p[i] = x;
                mloc = fmaxf(mloc, x);
            }
            mloc = fmaxf(mloc, __shfl_xor(mloc, 1));
            mloc = fmaxf(mloc, __shfl_xor(mloc, 2));
            mloc = fmaxf(mloc, __shfl_xor(mloc, 4));
            mloc = fmaxf(mloc, __shfl_xor(mloc, 8));
            float mold = m_s[qr];
            float mnew = fmaxf(mold, mloc);
            float alpha = __expf(mold - mnew);
            float lsum = 0.f;
            unsigned short hb[4], lb[4];
#pragma unroll
            for (int i = 0; i < 4; ++i) {
                float pe = __expf(p[i] - mnew);
                lsum += pe;
                unsigned short h = bf16_rne(pe);
                hb[i] = h;
                lb[i] = bf16_rne(pe - bf16_tof(h));
            }
            lsum += __shfl_xor(lsum, 1);
            lsum += __shfl_xor(lsum, 2);
            lsum += __shfl_xor(lsum, 4);
            lsum += __shfl_xor(lsum, 8);
            if (kc == 0) {
                m_s[qr]     = mnew;
                l_s[qr]     = l_s[qr] * alpha + lsum;
                alpha_s[qr] = alpha;
            }
            *(ushort4*)&ph_[qr][kc * 4] = *(ushort4*)&hb[0];
            *(ushort4*)&pl_[qr][kc * 4] = *(ushort4*)&lb[0];
        }

        __syncthreads();   // ===== sync2: staged tiles + P visible =====

        // ---- phase B (1): S1/S2 MFMA(ti) ----
        {
            f32x4 c1 = {0.f,0.f,0.f,0.f};
            f32x4 c2[2] = {{0.f,0.f,0.f,0.f},{0.f,0.f,0.f,0.f}};
            __builtin_amdgcn_s_setprio(1);
#pragma unroll
            for (int ks = 0; ks < 2; ++ks) {
                const int dof = ks * 32 + lg * 8;
                {
                    int krow = g4 * 16 + lr;
                    bf16x8 bh = *(const bf16x8*)&kh_[krow][dof];
                    bf16x8 bl = *(const bf16x8*)&kl_[krow][dof];
                    c1 = __builtin_amdgcn_mfma_f32_16x16x32_bf16(qfu_h[ks], bh, c1, 0, 0, 0);
                    c1 = __builtin_amdgcn_mfma_f32_16x16x32_bf16(qfu_h[ks], bl, c1, 0, 0, 0);
                    c1 = __builtin_amdgcn_mfma_f32_16x16x32_bf16(qfu_l[ks], bh, c1, 0, 0, 0);
                }
#pragma unroll
                for (int tt = 0; tt < 2; ++tt) {
                    int sl = (jb + (g4 * 2 + tt) * 16 + lr) & 127;
                    bf16x8 bh = *(const bf16x8*)&rh_[sl][dof];
                    bf16x8 bl = *(const bf16x8*)&rl_[sl][dof];
                    c2[tt] = __builtin_amdgcn_mfma_f32_16x16x32_bf16(qfv_h[ks], bh, c2[tt], 0, 0, 0);
                    c2[tt] = __builtin_amdgcn_mfma_f32_16x16x32_bf16(qfv_h[ks], bl, c2[tt], 0, 0, 0);
                    c2[tt] = __builtin_amdgcn_mfma_f32_16x16x32_bf16(qfv_l[ks], bh, c2[tt], 0, 0, 0);
                }
            }
            __builtin_amdgcn_s_setprio(0);
#pragma unroll
            for (int r = 0; r < 4; ++r)
                s1f[qi * 16 + lg * 4 + r][g4 * 16 + lr] = c1[r];
#pragma unroll
            for (int tt = 0; tt < 2; ++tt)
#pragma unroll
                for (int r = 0; r < 4; ++r)
                    s2f[qi * 16 + lg * 4 + r][(g4 * 2 + tt) * 16 + lr] = c2[tt][r];
        }
        // ---- phase B (2): PV MFMA(ti-1) ----
        if (ti > 0) {
            unsigned short (*pvh)[72] = ((ti - 1) & 1) ? qa_h : va_h;
            unsigned short (*pvl)[72] = ((ti - 1) & 1) ? qa_l : va_l;
            float ar[4];
#pragma unroll
            for (int r = 0; r < 4; ++r) ar[r] = alpha_s[qi * 16 + lg * 4 + r];
#pragma unroll
            for (int r = 0; r < 4; ++r) oc[r] *= ar[r];
            __builtin_amdgcn_s_setprio(1);
#pragma unroll
            for (int ks = 0; ks < 2; ++ks) {
                const int dof = ks * 32 + lg * 8;
                bf16x8 pa_h = *(const bf16x8*)&ph_[qi * 16 + lr][dof];
                bf16x8 pa_l = *(const bf16x8*)&pl_[qi * 16 + lr][dof];
                int drow = g4 * 16 + lr;
                bf16x8 bh = *(const bf16x8*)&pvh[drow][dof];
                bf16x8 bl = *(const bf16x8*)&pvl[drow][dof];
                oc = __builtin_amdgcn_mfma_f32_16x16x32_bf16(pa_h, bh, oc, 0, 0, 0);
                oc = __builtin_amdgcn_mfma_f32_16x16x32_bf16(pa_h, bl, oc, 0, 0, 0);
                oc = __builtin_amdgcn_mfma_f32_16x16x32_bf16(pa_l, bh, oc, 0, 0, 0);
            }
            __builtin_amdgcn_s_setprio(0);
        }
    }

    // ---- epilogue: softmax + PV for last tile ----
    __syncthreads();
    {
        const int k0p = (ntiles - 1) * 64;
        float p[4];
        float mloc = -1e30f;
        const int q = q0 + qr;
        float s1v[4];
        *(float4*)&s1v[0] = *(const float4*)&s1f[qr][kc * 4];
#pragma unroll
        for (int i = 0; i < 4; ++i) {
            int dk = kc * 4 + i;
            int t  = dk + 63 - qr;
            float x = (s1v[i] + s2f[qr][t]) * 0.125f;
            if (k0p + dk > q + M_LEN) x = -1e30f;
            p[i] = x;
            mloc = fmaxf(mloc, x);
        }
        mloc = fmaxf(mloc, __shfl_xor(mloc, 1));
        mloc = fmaxf(mloc, __shfl_xor(mloc, 2));
        mloc = fmaxf(mloc, __shfl_xor(mloc, 4));
        mloc = fmaxf(mloc, __shfl_xor(mloc, 8));
        float mold = m_s[qr];
        float mnew = fmaxf(mold, mloc);
        float alpha = __expf(mold - mnew);
        float lsum = 0.f;
        unsigned short hb[4], lb[4];
#pragma unroll
        for (int i = 0; i < 4; ++i) {
            float pe = __expf(p[i] - mnew);
            lsum += pe;
            unsigned short h = bf16_rne(pe);
            hb[i] = h;
            lb[i] = bf16_rne(pe - bf16_tof(h));
        }
        lsum += __shfl_xor(lsum, 1);
        lsum += __shfl_xor(lsum, 2);
        lsum += __shfl_xor(lsum, 4);
        lsum += __shfl_xor(lsum, 8);
        if (kc == 0) {
            l_s[qr]     = l_s[qr] * alpha + lsum;
            alpha_s[qr] = alpha;
        }
        *(ushort4*)&ph_[qr][kc * 4] = *(ushort4*)&hb[0];
        *(ushort4*)&pl_[qr][kc * 4] = *(ushort4*)&lb[0];
    }
    __syncthreads();
    {
        unsigned short (*pvh)[72] = ((ntiles - 1) & 1) ? qa_h : va_h;
        unsigned short (*pvl)[72] = ((ntiles - 1) & 1) ? qa_l : va_l;
        float ar[4];
#pragma unroll
        for (int r = 0; r < 4; ++r) ar[r] = alpha_s[qi * 16 + lg * 4 + r];
#pragma unroll
        for (int r = 0; r < 4; ++r) oc[r] *= ar[r];
#pragma unroll
        for (int ks = 0; ks < 2; ++ks) {
            const int dof = ks * 32 + lg * 8;
            bf16x8 pa_h = *(const bf16x8*)&ph_[qi * 16 + lr][dof];
            bf16x8 pa_l = *(const bf16x8*)&pl_[qi * 16 + lr][dof];
            int drow = g4 * 16 + lr;
            bf16x8 bh = *(const bf16x8*)&pvh[drow][dof];
            bf16x8 bl = *(const bf16x8*)&pvl[drow][dof];
            oc = __builtin_amdgcn_mfma_f32_16x16x32_bf16(pa_h, bh, oc, 0, 0, 0);
            oc = __builtin_amdgcn_mfma_f32_16x16x32_bf16(pa_h, bl, oc, 0, 0, 0);
            oc = __builtin_amdgcn_mfma_f32_16x16x32_bf16(pa_l, bh, oc, 0, 0, 0);
        }
    }

    // ---- store (b,q,n,d) ----
    {
        int dcol = g4 * 16 + lr;
#pragma unroll
        for (int r = 0; r < 4; ++r) {
            int qq = qi * 16 + lg * 4 + r;
            float val = oc[r] / l_s[qq];
            out[(((size_t)b * Q_LEN + q0 + qq) * N_HEADS + hn) * D_K + dcol] = val;
        }
    }
}

// ---------------------------------------------------------------------------
extern "C" void kernel_launch(void* const* d_in, const int* in_sizes, int n_in,
                              void* d_out, int out_size, void* d_ws, size_t ws_size,
                              hipStream_t stream) {
    (void)in_sizes; (void)n_in; (void)out_size; (void)ws_size;

    const float* inputs = (const float*)d_in[0];
    const float* mem    = (const float*)d_in[1];
    const float* r      = (const float*)d_in[2];
    const float* Wqkv   = (const float*)d_in[3];
    const float* bqkv   = (const float*)d_in[4];
    const float* Wr     = (const float*)d_in[5];
    const float* br     = (const float*)d_in[6];
    const float* Wo     = (const float*)d_in[7];
    const float* bo     = (const float*)d_in[8];
    const float* u      = (const float*)d_in[9];
    const float* v      = (const float*)d_in[10];
    float* out = (float*)d_out;

    unsigned short* wsh = (unsigned short*)d_ws;        // 8192 x 1536 (QKV hi)
    unsigned short* wsl = wsh + (size_t)8192 * 1536;    // 8192 x 1536 (QKV lo)
    unsigned short* rph = wsl + (size_t)8192 * 1536;    // 2048 x 512 (R hi)
    unsigned short* rpl = rph + (size_t)2048 * 512;     // 2048 x 512 (R lo)
    float* attn = (float*)(rpl + (size_t)2048 * 512);   // 4096 x 512 f32
    unsigned short* wqkvh = (unsigned short*)(attn + (size_t)4096 * 512);
    unsigned short* wqkvl = wqkvh + (size_t)1536 * 512;
    unsigned short* wrh   = wqkvl + (size_t)1536 * 512;
    unsigned short* wrl   = wrh   + (size_t)512 * 512;
    unsigned short* woh   = wrl   + (size_t)512 * 512;
    unsigned short* wol   = woh   + (size_t)512 * 512;

    hipLaunchKernelGGL(prep_w, dim3(24, 8), dim3(256), 0, stream, Wqkv, wqkvh, wqkvl, 1536);
    hipLaunchKernelGGL(prep_w, dim3(8, 8),  dim3(256), 0, stream, Wr,   wrh,   wrl,   512);
    hipLaunchKernelGGL(prep_w, dim3(8, 8),  dim3(256), 0, stream, Wo,   woh,   wol,   512);

    // 1) QKV projection -> split-bf16 output (wsh/wsl)
    hipLaunchKernelGGL(gemm_mfma, dim3(64, 12), dim3(256), 0, stream,
                       mem, inputs, wqkvh, wqkvl, bqkv, (float*)nullptr, wsh, wsl, 1536, 0);
    // 2) R projection -> split-bf16 output (rph/rpl)
    hipLaunchKernelGGL(gemm_mfma, dim3(16, 4), dim3(256), 0, stream,
                       r, r, wrh, wrl, br, (float*)nullptr, rph, rpl, 512, 1);
    // 3) fused relative attention (balanced 1-D grid)
    hipLaunchKernelGGL(attn_fused, dim3(512), dim3(1024), 0, stream,
                       wsh, wsl, rph, rpl, u, v, attn);
    // 4) output projection -> fp32 out
    hipLaunchKernelGGL(gemm_mfma, dim3(32, 4), dim3(256), 0, stream,
                       attn, attn, woh, wol, bo, out, (unsigned short*)nullptr,
                       (unsigned short*)nullptr, 512, 1);
}